// Round 6
// baseline (822.076 us; speedup 1.0000x reference)
//
#include <hip/hip_runtime.h>
#include <hip/hip_fp16.h>
#include <math.h>

#define NNODES 50000
#define NEDGES 800000
#define ETOT   (NEDGES + NNODES)
#define HIDC   32
#define NGRAPH 64
#define NCLS   10
#define SLOPE  0.2f
#define SCAN_BLOCKS ((NNODES + 255) / 256)   // 196

__device__ __forceinline__ float lrelu(float v) { return v > 0.f ? v : SLOPE * v; }

// ---------------- CSR build (by dst), includes self loops ----------------
__global__ void hist_kernel(const int* __restrict__ ei, int* __restrict__ deg) {
  int e = blockIdx.x * 256 + threadIdx.x;
  if (e >= ETOT) return;
  int d = (e < NEDGES) ? ei[NEDGES + e] : (e - NEDGES);
  atomicAdd(&deg[d], 1);
}

__global__ __launch_bounds__(256)
void scan_block_kernel(const int* __restrict__ deg, int* __restrict__ row_start,
                       int* __restrict__ bsum) {
  __shared__ int wsum[4];
  int i = blockIdx.x * 256 + threadIdx.x;
  int v = (i < NNODES) ? deg[i] : 0;
  int lane = threadIdx.x & 63, w = threadIdx.x >> 6;
  int x = v;
  #pragma unroll
  for (int d = 1; d < 64; d <<= 1) {
    int y = __shfl_up(x, d);
    if (lane >= d) x += y;
  }
  if (lane == 63) wsum[w] = x;
  __syncthreads();
  int woff = 0;
  #pragma unroll
  for (int j = 0; j < 4; ++j) if (j < w) woff += wsum[j];
  int incl = x + woff;
  if (i < NNODES) row_start[i] = incl - v;
  if (threadIdx.x == 255) bsum[blockIdx.x] = incl;
}

__global__ __launch_bounds__(256)
void scan_sums_kernel(const int* __restrict__ bsum, int* __restrict__ boff) {
  __shared__ int wsum[4];
  int tid = threadIdx.x;
  int v = (tid < SCAN_BLOCKS) ? bsum[tid] : 0;
  int lane = tid & 63, w = tid >> 6;
  int x = v;
  #pragma unroll
  for (int d = 1; d < 64; d <<= 1) {
    int y = __shfl_up(x, d);
    if (lane >= d) x += y;
  }
  if (lane == 63) wsum[w] = x;
  __syncthreads();
  int woff = 0;
  #pragma unroll
  for (int j = 0; j < 4; ++j) if (j < w) woff += wsum[j];
  if (tid < SCAN_BLOCKS) boff[tid] = (x + woff) - v;
}

__global__ __launch_bounds__(256)
void scan_add_kernel(const int* __restrict__ boff, int* __restrict__ row_start) {
  int i = blockIdx.x * 256 + threadIdx.x;
  if (i < NNODES) row_start[i] += boff[blockIdx.x];
  if (i == 0) row_start[NNODES] = ETOT;
}

__global__ void scatter_kernel(const int* __restrict__ ei, const int* __restrict__ row_start,
                               int* __restrict__ cursor, int* __restrict__ col_src) {
  int e = blockIdx.x * 256 + threadIdx.x;
  if (e >= ETOT) return;
  int s, d;
  if (e < NEDGES) { s = ei[e]; d = ei[NEDGES + e]; }
  else { s = d = e - NEDGES; }
  int pos = atomicAdd(&cursor[d], 1);
  col_src[row_start[d] + pos] = s;
}

// ---------------- tiny weight-composition kernels (run once, ~µs) ----------------
// C[M,N] = A[M,K] @ B[K,N]
__global__ void wprod_kernel(const float* __restrict__ A, const float* __restrict__ B,
                             float* __restrict__ C, int M, int K, int N) {
  int col = blockIdx.x * 16 + (threadIdx.x & 15);
  int row = blockIdx.y * 16 + (threadIdx.x >> 4);
  if (row >= M || col >= N) return;
  float acc = 0.f;
  for (int k = 0; k < K; ++k) acc = fmaf(A[row * K + k], B[k * N + col], acc);
  C[row * N + col] = acc;
}

// out[j] = v @ W[:,j] + bias[j]
__global__ void vecmat_kernel(const float* __restrict__ v, const float* __restrict__ W,
                              const float* __restrict__ bias, float* __restrict__ out,
                              int K, int N) {
  int j = blockIdx.x * 256 + threadIdx.x;
  if (j >= N) return;
  float acc = bias ? bias[j] : 0.f;
  for (int k = 0; k < K; ++k) acc = fmaf(v[k], W[k * N + j], acc);
  out[j] = acc;
}

// Ws[r][j] = sum_c W[r, h*32+c] * a[h][c],  h=j&3, a = as_ (j<4) or ad_ (j>=4)
// W has row stride 128. din rows. (din=1 folds a bias vector.)
__global__ void score_fold_kernel(const float* __restrict__ W, const float* __restrict__ as_,
                                  const float* __restrict__ ad_, float* __restrict__ Ws, int din) {
  int t = blockIdx.x * 256 + threadIdx.x;
  if (t >= din * 8) return;
  int r = t >> 3, j = t & 7, h = j & 3;
  const float* a = (j < 4) ? as_ : ad_;
  float s = 0.f;
  for (int c = 0; c < 32; ++c) s = fmaf(W[r * 128 + h * 32 + c], a[h * 32 + c], s);
  Ws[t] = s;
}

// ---------------- fp32 tiled GEMM -> fp16 output [M,128] ----------------
__global__ __launch_bounds__(256)
void gemm_h16(const float* __restrict__ A, const float* __restrict__ B,
              const float* __restrict__ bias, __half* __restrict__ Ch,
              int M, int K) {
  __shared__ float As[32][68];
  __shared__ float Bs[32][68];
  int row0 = blockIdx.x * 64, col0 = blockIdx.y * 64;
  int tid = threadIdx.x;
  int tx = tid & 15;
  int ty = tid >> 4;
  float acc[4][4] = {};
  for (int k0 = 0; k0 < K; k0 += 32) {
    #pragma unroll
    for (int i = 0; i < 8; ++i) {
      int idx = tid + i * 256;
      int r = idx >> 5, c = idx & 31;
      int gr = row0 + r;
      As[c][r] = (gr < M && (k0 + c) < K) ? A[(size_t)gr * K + k0 + c] : 0.f;
    }
    #pragma unroll
    for (int i = 0; i < 8; ++i) {
      int idx = tid + i * 256;
      int r = idx >> 6, c = idx & 63;
      Bs[r][c] = ((k0 + r) < K) ? B[(size_t)(k0 + r) * 128 + col0 + c] : 0.f;
    }
    __syncthreads();
    #pragma unroll
    for (int k = 0; k < 32; ++k) {
      float a4[4], b4[4];
      #pragma unroll
      for (int i = 0; i < 4; ++i) a4[i] = As[k][ty * 4 + i];
      #pragma unroll
      for (int j = 0; j < 4; ++j) b4[j] = Bs[k][tx * 4 + j];
      #pragma unroll
      for (int i = 0; i < 4; ++i)
        #pragma unroll
        for (int j = 0; j < 4; ++j)
          acc[i][j] = fmaf(a4[i], b4[j], acc[i][j]);
    }
    __syncthreads();
  }
  #pragma unroll
  for (int i = 0; i < 4; ++i) {
    int gr = row0 + ty * 4 + i;
    if (gr >= M) continue;
    int gc0 = col0 + tx * 4;
    float v0 = acc[i][0] + (bias ? bias[gc0]     : 0.f);
    float v1 = acc[i][1] + (bias ? bias[gc0 + 1] : 0.f);
    float v2 = acc[i][2] + (bias ? bias[gc0 + 2] : 0.f);
    float v3 = acc[i][3] + (bias ? bias[gc0 + 3] : 0.f);
    __half2* hp = (__half2*)(Ch + (size_t)gr * 128 + gc0);
    hp[0] = __floats2half2_rn(v0, v1);
    hp[1] = __floats2half2_rn(v2, v3);
  }
}

// ---------------- direct per-node scores: sc = A @ Ws (+soff), 8 cols ----------------
__global__ __launch_bounds__(256)
void scores_direct(const float* __restrict__ A, const float* __restrict__ Wsg,
                   const float* __restrict__ soff,
                   float* __restrict__ scs, float* __restrict__ scd, int K) {
  __shared__ float ws[8][132];   // transposed, padded: bank-friendly
  int tid = threadIdx.x;
  for (int idx = tid; idx < K * 8; idx += 256)
    ws[idx & 7][idx >> 3] = Wsg[idx];
  __syncthreads();
  int wave = tid >> 6, lane = tid & 63;
  int node = blockIdx.x * 4 + wave;
  if (node >= NNODES) return;
  float x1 = (lane < K) ? A[(size_t)node * K + lane] : 0.f;
  float x2 = (lane + 64 < K) ? A[(size_t)node * K + lane + 64] : 0.f;
  float acc[8];
  #pragma unroll
  for (int j = 0; j < 8; ++j) {
    float a = (lane < K) ? x1 * ws[j][lane] : 0.f;
    if (lane + 64 < K) a = fmaf(x2, ws[j][lane + 64], a);
    acc[j] = a;
  }
  #pragma unroll
  for (int d = 32; d >= 1; d >>= 1)
    #pragma unroll
    for (int j = 0; j < 8; ++j) acc[j] += __shfl_xor(acc[j], d);
  if (lane == 0) {
    float o0 = soff ? soff[0] : 0.f, o1 = soff ? soff[1] : 0.f;
    float o2 = soff ? soff[2] : 0.f, o3 = soff ? soff[3] : 0.f;
    float o4 = soff ? soff[4] : 0.f, o5 = soff ? soff[5] : 0.f;
    float o6 = soff ? soff[6] : 0.f, o7 = soff ? soff[7] : 0.f;
    *(float4*)(scs + (size_t)node * 4) = make_float4(acc[0] + o0, acc[1] + o1, acc[2] + o2, acc[3] + o3);
    *(float4*)(scd + (size_t)node * 4) = make_float4(acc[4] + o4, acc[5] + o5, acc[6] + o6, acc[7] + o7);
  }
}

// ---------------- fused GAT edge kernel (LDS-staged alphas, 16 lanes/edge) ----------------
__global__ __launch_bounds__(256)
void gat_edge_kernel(const __half2* __restrict__ hproj_h,
                     const float* __restrict__ scs, const float* __restrict__ scd,
                     const int* __restrict__ row_start, const int* __restrict__ col_src,
                     const float* __restrict__ bias, float* __restrict__ hout) {
  __shared__ int src_sh[4][64];
  __shared__ __align__(16) float al_sh[4][256];
  int wave = threadIdx.x >> 6, lane = threadIdx.x & 63;
  int node = blockIdx.x * 4 + wave;
  if (node >= NNODES) return;
  int s = row_start[node], e = row_start[node + 1];
  int deg = e - s;
  float4 sd = *(const float4*)(scd + (size_t)node * 4);
  const uint4* hp4 = (const uint4*)hproj_h;   // 16 x uint4 per node row (128 fp16)

  if (deg <= 64) {
    int i = s + lane;
    bool valid = i < e;
    int srcv = 0;
    float4 ss = make_float4(0.f, 0.f, 0.f, 0.f);
    if (valid) {
      srcv = col_src[i];
      ss = *(const float4*)(scs + (size_t)srcv * 4);
    }
    float e0 = lrelu(ss.x + sd.x), e1 = lrelu(ss.y + sd.y);
    float e2 = lrelu(ss.z + sd.z), e3 = lrelu(ss.w + sd.w);
    float m0 = valid ? e0 : -INFINITY, m1 = valid ? e1 : -INFINITY;
    float m2 = valid ? e2 : -INFINITY, m3 = valid ? e3 : -INFINITY;
    #pragma unroll
    for (int d = 32; d >= 1; d >>= 1) {
      m0 = fmaxf(m0, __shfl_xor(m0, d));
      m1 = fmaxf(m1, __shfl_xor(m1, d));
      m2 = fmaxf(m2, __shfl_xor(m2, d));
      m3 = fmaxf(m3, __shfl_xor(m3, d));
    }
    float a0 = valid ? __expf(e0 - m0) : 0.f;
    float a1 = valid ? __expf(e1 - m1) : 0.f;
    float a2 = valid ? __expf(e2 - m2) : 0.f;
    float a3 = valid ? __expf(e3 - m3) : 0.f;
    float d0 = a0, d1 = a1, d2 = a2, d3 = a3;
    #pragma unroll
    for (int d = 32; d >= 1; d >>= 1) {
      d0 += __shfl_xor(d0, d);
      d1 += __shfl_xor(d1, d);
      d2 += __shfl_xor(d2, d);
      d3 += __shfl_xor(d3, d);
    }
    src_sh[wave][lane] = srcv;
    *(float4*)&al_sh[wave][lane * 4] = make_float4(a0, a1, a2, a3);

    int g = lane >> 4;
    int r = lane & 15;
    int head = r >> 2;
    float acc[8] = {};
    int ng = (deg + 3) >> 2;
    for (int jg = 0; jg < ng; ++jg) {
      int j = jg * 4 + g;
      int src = src_sh[wave][j];
      float al = al_sh[wave][j * 4 + head];
      uint4 p = hp4[(size_t)src * 16 + r];
      float2 f0 = __half22float2(*(__half2*)&p.x);
      float2 f1 = __half22float2(*(__half2*)&p.y);
      float2 f2 = __half22float2(*(__half2*)&p.z);
      float2 f3 = __half22float2(*(__half2*)&p.w);
      acc[0] = fmaf(al, f0.x, acc[0]); acc[1] = fmaf(al, f0.y, acc[1]);
      acc[2] = fmaf(al, f1.x, acc[2]); acc[3] = fmaf(al, f1.y, acc[3]);
      acc[4] = fmaf(al, f2.x, acc[4]); acc[5] = fmaf(al, f2.y, acc[5]);
      acc[6] = fmaf(al, f3.x, acc[6]); acc[7] = fmaf(al, f3.y, acc[7]);
    }
    float den = (head == 0) ? d0 : (head == 1) ? d1 : (head == 2) ? d2 : d3;
    float rd = 1.f / fmaxf(den, 1e-16f);
    #pragma unroll
    for (int k = 0; k < 8; ++k) acc[k] *= rd;
    #pragma unroll
    for (int d = 4; d <= 32; d <<= 1) {
      #pragma unroll
      for (int k = 0; k < 8; ++k) acc[k] += __shfl_xor(acc[k], d);
    }
    if (lane < 4) {
      float o[8];
      #pragma unroll
      for (int k = 0; k < 8; ++k) {
        float v = acc[k] * 0.25f + bias[8 * lane + k];
        o[k] = v > 0.f ? v : expm1f(v);
      }
      float* op = hout + (size_t)node * 32 + 8 * lane;
      *(float4*)op       = make_float4(o[0], o[1], o[2], o[3]);
      *(float4*)(op + 4) = make_float4(o[4], o[5], o[6], o[7]);
    }
  } else {
    float m0 = -INFINITY, m1 = -INFINITY, m2 = -INFINITY, m3 = -INFINITY;
    for (int i = s + lane; i < e; i += 64) {
      int src = col_src[i];
      float4 ss = *(const float4*)(scs + (size_t)src * 4);
      m0 = fmaxf(m0, lrelu(ss.x + sd.x));
      m1 = fmaxf(m1, lrelu(ss.y + sd.y));
      m2 = fmaxf(m2, lrelu(ss.z + sd.z));
      m3 = fmaxf(m3, lrelu(ss.w + sd.w));
    }
    #pragma unroll
    for (int d = 32; d >= 1; d >>= 1) {
      m0 = fmaxf(m0, __shfl_xor(m0, d));
      m1 = fmaxf(m1, __shfl_xor(m1, d));
      m2 = fmaxf(m2, __shfl_xor(m2, d));
      m3 = fmaxf(m3, __shfl_xor(m3, d));
    }
    int g = lane >> 4, r = lane & 15, head = r >> 2;
    float den0 = 0, den1 = 0, den2 = 0, den3 = 0;
    float acc[8] = {};
    for (int base = s; base < e; base += 64) {
      int i = base + lane;
      bool valid = i < e;
      int srcv = 0;
      float a0 = 0, a1 = 0, a2 = 0, a3 = 0;
      if (valid) {
        srcv = col_src[i];
        float4 ss = *(const float4*)(scs + (size_t)srcv * 4);
        a0 = __expf(lrelu(ss.x + sd.x) - m0);
        a1 = __expf(lrelu(ss.y + sd.y) - m1);
        a2 = __expf(lrelu(ss.z + sd.z) - m2);
        a3 = __expf(lrelu(ss.w + sd.w) - m3);
        den0 += a0; den1 += a1; den2 += a2; den3 += a3;
      }
      src_sh[wave][lane] = srcv;
      *(float4*)&al_sh[wave][lane * 4] = make_float4(a0, a1, a2, a3);
      int cnt = min(64, e - base);
      int ngc = (cnt + 3) >> 2;
      for (int jg = 0; jg < ngc; ++jg) {
        int j = jg * 4 + g;
        int src = src_sh[wave][j];
        float al = al_sh[wave][j * 4 + head];
        uint4 p = hp4[(size_t)src * 16 + r];
        float2 f0 = __half22float2(*(__half2*)&p.x);
        float2 f1 = __half22float2(*(__half2*)&p.y);
        float2 f2 = __half22float2(*(__half2*)&p.z);
        float2 f3 = __half22float2(*(__half2*)&p.w);
        acc[0] = fmaf(al, f0.x, acc[0]); acc[1] = fmaf(al, f0.y, acc[1]);
        acc[2] = fmaf(al, f1.x, acc[2]); acc[3] = fmaf(al, f1.y, acc[3]);
        acc[4] = fmaf(al, f2.x, acc[4]); acc[5] = fmaf(al, f2.y, acc[5]);
        acc[6] = fmaf(al, f3.x, acc[6]); acc[7] = fmaf(al, f3.y, acc[7]);
      }
    }
    #pragma unroll
    for (int d = 32; d >= 1; d >>= 1) {
      den0 += __shfl_xor(den0, d);
      den1 += __shfl_xor(den1, d);
      den2 += __shfl_xor(den2, d);
      den3 += __shfl_xor(den3, d);
    }
    float den = (head == 0) ? den0 : (head == 1) ? den1 : (head == 2) ? den2 : den3;
    float rd = 1.f / fmaxf(den, 1e-16f);
    #pragma unroll
    for (int k = 0; k < 8; ++k) acc[k] *= rd;
    #pragma unroll
    for (int d = 4; d <= 32; d <<= 1) {
      #pragma unroll
      for (int k = 0; k < 8; ++k) acc[k] += __shfl_xor(acc[k], d);
    }
    if (lane < 4) {
      float o[8];
      #pragma unroll
      for (int k = 0; k < 8; ++k) {
        float v = acc[k] * 0.25f + bias[8 * lane + k];
        o[k] = v > 0.f ? v : expm1f(v);
      }
      float* op = hout + (size_t)node * 32 + 8 * lane;
      *(float4*)op       = make_float4(o[0], o[1], o[2], o[3]);
      *(float4*)(op + 4) = make_float4(o[4], o[5], o[6], o[7]);
    }
  }
}

// ---------------- hierarchical global mean pool ----------------
#define POOL_BLOCKS 128
__global__ __launch_bounds__(256)
void pool_kernel(const float* __restrict__ h, const int* __restrict__ batch,
                 float* __restrict__ pooled, float* __restrict__ cnt) {
  __shared__ float acc[NGRAPH][HIDC];
  __shared__ float ccnt[NGRAPH];
  int tid = threadIdx.x;
  const int chunk = (NNODES + POOL_BLOCKS - 1) / POOL_BLOCKS;
  int n0 = blockIdx.x * chunk;
  int n1 = min(n0 + chunk, NNODES);
  if (n0 >= NNODES) return;
  int g0 = batch[n0], g1 = batch[n1 - 1];
  int rows = g1 - g0 + 1;
  for (int idx = tid; idx < rows * HIDC; idx += 256)
    acc[g0 + (idx >> 5)][idx & 31] = 0.f;
  for (int g = tid; g < rows; g += 256) ccnt[g0 + g] = 0.f;
  __syncthreads();
  int c = tid & 31;
  for (int node = n0 + (tid >> 5); node < n1; node += 8) {
    int g = batch[node];
    atomicAdd(&acc[g][c], h[(size_t)node * HIDC + c]);
    if (c == 0) atomicAdd(&ccnt[g], 1.f);
  }
  __syncthreads();
  for (int idx = tid; idx < rows * HIDC; idx += 256) {
    int g = g0 + (idx >> 5), cc = idx & 31;
    atomicAdd(&pooled[g * HIDC + cc], acc[g][cc]);
  }
  for (int g = tid; g < rows; g += 256) atomicAdd(&cnt[g0 + g], ccnt[g0 + g]);
}

__global__ void final_kernel(const float* __restrict__ pooled, const float* __restrict__ cnt,
                             const float* __restrict__ w, const float* __restrict__ b,
                             float* __restrict__ out) {
  int t = threadIdx.x;
  if (t >= NGRAPH * NCLS) return;
  int g = t / NCLS, j = t - g * NCLS;
  float inv = 1.f / fmaxf(cnt[g], 1.f);
  float acc = 0.f;
  #pragma unroll
  for (int c = 0; c < HIDC; ++c)
    acc = fmaf(pooled[g * HIDC + c], w[c * NCLS + j], acc);
  out[t] = acc * inv + b[j];
}

extern "C" void kernel_launch(void* const* d_in, const int* in_sizes, int n_in,
                              void* d_out, int out_size, void* d_ws, size_t ws_size,
                              hipStream_t stream) {
  const float* x      = (const float*)d_in[0];
  const int*   ei     = (const int*)d_in[1];
  const int*   batch  = (const int*)d_in[2];
  const float* enc1_w = (const float*)d_in[3];
  const float* enc1_b = (const float*)d_in[4];
  const float* enc2_w = (const float*)d_in[5];
  const float* enc2_b = (const float*)d_in[6];
  const float* lin1_w = (const float*)d_in[7];
  const float* lin1_b = (const float*)d_in[8];
  const float* gw[4]  = {(const float*)d_in[9],  (const float*)d_in[13], (const float*)d_in[17], (const float*)d_in[21]};
  const float* gas[4] = {(const float*)d_in[10], (const float*)d_in[14], (const float*)d_in[18], (const float*)d_in[22]};
  const float* gad[4] = {(const float*)d_in[11], (const float*)d_in[15], (const float*)d_in[19], (const float*)d_in[23]};
  const float* gb[4]  = {(const float*)d_in[12], (const float*)d_in[16], (const float*)d_in[20], (const float*)d_in[24]};
  float* out = (float*)d_out;

  // workspace: fp16 payload first (16B aligned), then fp32, then ints
  __half* hproj_h = (__half*)d_ws;                          // N*128 fp16
  float*  fws     = (float*)(hproj_h + (size_t)NNODES * 128);
  float* hsmall = fws;                                      // N*32
  float* scs    = hsmall + (size_t)NNODES * 32;             // N*4
  float* scd    = scs    + (size_t)NNODES * 4;              // N*4
  float* pooled = scd    + (size_t)NNODES * 4;              // 64*32
  float* cnt    = pooled + NGRAPH * HIDC;                   // 64
  float* T1     = cnt + NGRAPH;                             // 128*256
  float* Wc     = T1 + 128 * 256;                           // 128*128
  float* b2c    = Wc + 128 * 128;                           // 256
  float* bc     = b2c + 256;                                // 128
  float* soff1  = bc + 128;                                 // 8
  float* Ws1    = soff1 + 8;                                // 128*8
  float* Ws2    = Ws1 + 128 * 8;                            // 32*8
  float* Ws3    = Ws2 + 32 * 8;
  float* Ws4    = Ws3 + 32 * 8;
  int* deg       = (int*)(Ws4 + 32 * 8);                    // N
  int* row_start = deg + NNODES;                            // N+1
  int* col_src   = row_start + NNODES + 1;                  // ETOT
  int* bsum      = col_src + ETOT;                          // 196
  int* boff      = bsum + SCAN_BLOCKS;                      // 196

  // --- weight composition (tiny) ---
  // T1 = enc1_w @ enc2_w ; Wc = T1 @ g1_w ; b2c = enc1_b@enc2_w + enc2_b ; bc = b2c@g1_w
  wprod_kernel<<<dim3(16, 8), 256, 0, stream>>>(enc1_w, enc2_w, T1, 128, 128, 256);
  wprod_kernel<<<dim3(8, 8), 256, 0, stream>>>(T1, gw[0], Wc, 128, 256, 128);
  vecmat_kernel<<<1, 256, 0, stream>>>(enc1_b, enc2_w, enc2_b, b2c, 128, 256);
  vecmat_kernel<<<1, 256, 0, stream>>>(b2c, gw[0], nullptr, bc, 256, 128);
  // score folds: Ws_L = W_L @ F_L ; soff1 = bc @ F_1
  score_fold_kernel<<<4, 256, 0, stream>>>(Wc, gas[0], gad[0], Ws1, 128);
  score_fold_kernel<<<1, 256, 0, stream>>>(bc, gas[0], gad[0], soff1, 1);
  score_fold_kernel<<<1, 256, 0, stream>>>(gw[1], gas[1], gad[1], Ws2, 32);
  score_fold_kernel<<<1, 256, 0, stream>>>(gw[2], gas[2], gad[2], Ws3, 32);
  score_fold_kernel<<<1, 256, 0, stream>>>(gw[3], gas[3], gad[3], Ws4, 32);

  // --- CSR build (parallel scan) ---
  hipMemsetAsync(deg, 0, NNODES * sizeof(int), stream);
  hist_kernel<<<(ETOT + 255) / 256, 256, 0, stream>>>(ei, deg);
  scan_block_kernel<<<SCAN_BLOCKS, 256, 0, stream>>>(deg, row_start, bsum);
  scan_sums_kernel<<<1, 256, 0, stream>>>(bsum, boff);
  scan_add_kernel<<<SCAN_BLOCKS, 256, 0, stream>>>(boff, row_start);
  hipMemsetAsync(deg, 0, NNODES * sizeof(int), stream);
  scatter_kernel<<<(ETOT + 255) / 256, 256, 0, stream>>>(ei, row_start, deg, col_src);

  dim3 gproj((NNODES + 63) / 64, 2);
  int nodeblocks = (NNODES + 3) / 4;

  // --- layer 1 (composite: enc1+enc2+g1 projection in one GEMM) ---
  gemm_h16<<<gproj, 256, 0, stream>>>(x, Wc, bc, hproj_h, NNODES, 128);
  scores_direct<<<nodeblocks, 256, 0, stream>>>(x, Ws1, soff1, scs, scd, 128);
  gat_edge_kernel<<<nodeblocks, 256, 0, stream>>>((const __half2*)hproj_h, scs, scd, row_start, col_src, gb[0], hsmall);

  // --- layers 2..4 ---
  const float* WsL[4] = {Ws1, Ws2, Ws3, Ws4};
  for (int L = 1; L < 4; ++L) {
    gemm_h16<<<gproj, 256, 0, stream>>>(hsmall, gw[L], nullptr, hproj_h, NNODES, 32);
    scores_direct<<<nodeblocks, 256, 0, stream>>>(hsmall, WsL[L], nullptr, scs, scd, 32);
    gat_edge_kernel<<<nodeblocks, 256, 0, stream>>>((const __half2*)hproj_h, scs, scd, row_start, col_src, gb[L], hsmall);
  }

  // --- pooling + classifier ---
  hipMemsetAsync(pooled, 0, (NGRAPH * HIDC + NGRAPH) * sizeof(float), stream);
  pool_kernel<<<POOL_BLOCKS, 256, 0, stream>>>(hsmall, batch, pooled, cnt);
  final_kernel<<<1, 640, 0, stream>>>(pooled, cnt, lin1_w, lin1_b, out);
}

// Round 7
// 682.705 us; speedup vs baseline: 1.2041x; 1.2041x over previous
//
#include <hip/hip_runtime.h>
#include <hip/hip_fp16.h>
#include <math.h>

#define NNODES 50000
#define NEDGES 800000
#define ETOT   (NEDGES + NNODES)
#define HIDC   32
#define NGRAPH 64
#define NCLS   10
#define SLOPE  0.2f
#define SCAN_BLOCKS ((NNODES + 255) / 256)   // 196

__device__ __forceinline__ float lrelu(float v) { return v > 0.f ? v : SLOPE * v; }

// ---------------- CSR build (by dst), includes self loops ----------------
__global__ void hist_kernel(const int* __restrict__ ei, int* __restrict__ deg) {
  int e = blockIdx.x * 256 + threadIdx.x;
  if (e >= ETOT) return;
  int d = (e < NEDGES) ? ei[NEDGES + e] : (e - NEDGES);
  atomicAdd(&deg[d], 1);
}

__global__ __launch_bounds__(256)
void scan_block_kernel(const int* __restrict__ deg, int* __restrict__ row_start,
                       int* __restrict__ bsum) {
  __shared__ int wsum[4];
  int i = blockIdx.x * 256 + threadIdx.x;
  int v = (i < NNODES) ? deg[i] : 0;
  int lane = threadIdx.x & 63, w = threadIdx.x >> 6;
  int x = v;
  #pragma unroll
  for (int d = 1; d < 64; d <<= 1) {
    int y = __shfl_up(x, d);
    if (lane >= d) x += y;
  }
  if (lane == 63) wsum[w] = x;
  __syncthreads();
  int woff = 0;
  #pragma unroll
  for (int j = 0; j < 4; ++j) if (j < w) woff += wsum[j];
  int incl = x + woff;
  if (i < NNODES) row_start[i] = incl - v;
  if (threadIdx.x == 255) bsum[blockIdx.x] = incl;
}

__global__ __launch_bounds__(256)
void scan_sums_kernel(const int* __restrict__ bsum, int* __restrict__ boff) {
  __shared__ int wsum[4];
  int tid = threadIdx.x;
  int v = (tid < SCAN_BLOCKS) ? bsum[tid] : 0;
  int lane = tid & 63, w = tid >> 6;
  int x = v;
  #pragma unroll
  for (int d = 1; d < 64; d <<= 1) {
    int y = __shfl_up(x, d);
    if (lane >= d) x += y;
  }
  if (lane == 63) wsum[w] = x;
  __syncthreads();
  int woff = 0;
  #pragma unroll
  for (int j = 0; j < 4; ++j) if (j < w) woff += wsum[j];
  if (tid < SCAN_BLOCKS) boff[tid] = (x + woff) - v;
}

__global__ __launch_bounds__(256)
void scan_add_kernel(const int* __restrict__ boff, int* __restrict__ row_start) {
  int i = blockIdx.x * 256 + threadIdx.x;
  if (i < NNODES) row_start[i] += boff[blockIdx.x];
  if (i == 0) row_start[NNODES] = ETOT;
}

__global__ void scatter_kernel(const int* __restrict__ ei, const int* __restrict__ row_start,
                               int* __restrict__ cursor, int* __restrict__ col_src) {
  int e = blockIdx.x * 256 + threadIdx.x;
  if (e >= ETOT) return;
  int s, d;
  if (e < NEDGES) { s = ei[e]; d = ei[NEDGES + e]; }
  else { s = d = e - NEDGES; }
  int pos = atomicAdd(&cursor[d], 1);
  col_src[row_start[d] + pos] = s;
}

// ---------------- fp32 tiled GEMM (fp32 out), M,N mult of 64, K mult of 32 ----------------
__global__ __launch_bounds__(256)
void gemm_f32(const float* __restrict__ A, const float* __restrict__ B,
              const float* __restrict__ bias, float* __restrict__ C,
              int M, int K, int N) {
  __shared__ float As[32][68];
  __shared__ float Bs[32][68];
  int row0 = blockIdx.x * 64, col0 = blockIdx.y * 64;
  int tid = threadIdx.x;
  int tx = tid & 15, ty = tid >> 4;
  float acc[4][4] = {};
  for (int k0 = 0; k0 < K; k0 += 32) {
    #pragma unroll
    for (int i = 0; i < 8; ++i) {
      int idx = tid + i * 256;
      int r = idx >> 5, c = idx & 31;
      int gr = row0 + r;
      As[c][r] = (gr < M) ? A[(size_t)gr * K + k0 + c] : 0.f;
    }
    #pragma unroll
    for (int i = 0; i < 8; ++i) {
      int idx = tid + i * 256;
      int r = idx >> 6, c = idx & 63;
      Bs[r][c] = B[(size_t)(k0 + r) * N + col0 + c];
    }
    __syncthreads();
    #pragma unroll
    for (int k = 0; k < 32; ++k) {
      float a4[4], b4[4];
      #pragma unroll
      for (int i = 0; i < 4; ++i) a4[i] = As[k][ty * 4 + i];
      #pragma unroll
      for (int j = 0; j < 4; ++j) b4[j] = Bs[k][tx * 4 + j];
      #pragma unroll
      for (int i = 0; i < 4; ++i)
        #pragma unroll
        for (int j = 0; j < 4; ++j)
          acc[i][j] = fmaf(a4[i], b4[j], acc[i][j]);
    }
    __syncthreads();
  }
  #pragma unroll
  for (int i = 0; i < 4; ++i) {
    int gr = row0 + ty * 4 + i;
    if (gr >= M) continue;
    #pragma unroll
    for (int j = 0; j < 4; ++j) {
      int gc = col0 + tx * 4 + j;
      C[(size_t)gr * N + gc] = acc[i][j] + (bias ? bias[gc] : 0.f);
    }
  }
}

// out[j] = v @ W[:,j] + bias[j]
__global__ void vecmat_kernel(const float* __restrict__ v, const float* __restrict__ W,
                              const float* __restrict__ bias, float* __restrict__ out,
                              int K, int N) {
  int j = blockIdx.x * 256 + threadIdx.x;
  if (j >= N) return;
  float acc = bias ? bias[j] : 0.f;
  for (int k = 0; k < K; ++k) acc = fmaf(v[k], W[k * N + j], acc);
  out[j] = acc;
}

// Ws[r][j] = sum_c W[r, h*32+c] * a[h][c],  h=j&3, a = as_ (j<4) or ad_ (j>=4)
__global__ void score_fold_kernel(const float* __restrict__ W, const float* __restrict__ as_,
                                  const float* __restrict__ ad_, float* __restrict__ Ws, int din) {
  int t = blockIdx.x * 256 + threadIdx.x;
  if (t >= din * 8) return;
  int r = t >> 3, j = t & 7, h = j & 3;
  const float* a = (j < 4) ? as_ : ad_;
  float s = 0.f;
  for (int c = 0; c < 32; ++c) s = fmaf(W[r * 128 + h * 32 + c], a[h * 32 + c], s);
  Ws[t] = s;
}

// ---------------- fp32 tiled GEMM -> fp16 output [M,128] ----------------
__global__ __launch_bounds__(256)
void gemm_h16(const float* __restrict__ A, const float* __restrict__ B,
              const float* __restrict__ bias, __half* __restrict__ Ch,
              int M, int K) {
  __shared__ float As[32][68];
  __shared__ float Bs[32][68];
  int row0 = blockIdx.x * 64, col0 = blockIdx.y * 64;
  int tid = threadIdx.x;
  int tx = tid & 15, ty = tid >> 4;
  float acc[4][4] = {};
  for (int k0 = 0; k0 < K; k0 += 32) {
    #pragma unroll
    for (int i = 0; i < 8; ++i) {
      int idx = tid + i * 256;
      int r = idx >> 5, c = idx & 31;
      int gr = row0 + r;
      As[c][r] = (gr < M && (k0 + c) < K) ? A[(size_t)gr * K + k0 + c] : 0.f;
    }
    #pragma unroll
    for (int i = 0; i < 8; ++i) {
      int idx = tid + i * 256;
      int r = idx >> 6, c = idx & 63;
      Bs[r][c] = ((k0 + r) < K) ? B[(size_t)(k0 + r) * 128 + col0 + c] : 0.f;
    }
    __syncthreads();
    #pragma unroll
    for (int k = 0; k < 32; ++k) {
      float a4[4], b4[4];
      #pragma unroll
      for (int i = 0; i < 4; ++i) a4[i] = As[k][ty * 4 + i];
      #pragma unroll
      for (int j = 0; j < 4; ++j) b4[j] = Bs[k][tx * 4 + j];
      #pragma unroll
      for (int i = 0; i < 4; ++i)
        #pragma unroll
        for (int j = 0; j < 4; ++j)
          acc[i][j] = fmaf(a4[i], b4[j], acc[i][j]);
    }
    __syncthreads();
  }
  #pragma unroll
  for (int i = 0; i < 4; ++i) {
    int gr = row0 + ty * 4 + i;
    if (gr >= M) continue;
    int gc0 = col0 + tx * 4;
    float v0 = acc[i][0] + (bias ? bias[gc0]     : 0.f);
    float v1 = acc[i][1] + (bias ? bias[gc0 + 1] : 0.f);
    float v2 = acc[i][2] + (bias ? bias[gc0 + 2] : 0.f);
    float v3 = acc[i][3] + (bias ? bias[gc0 + 3] : 0.f);
    __half2* hp = (__half2*)(Ch + (size_t)gr * 128 + gc0);
    hp[0] = __floats2half2_rn(v0, v1);
    hp[1] = __floats2half2_rn(v2, v3);
  }
}

// ---------------- direct per-node scores: sc = A @ Ws (+soff), 8 cols ----------------
__global__ __launch_bounds__(256)
void scores_direct(const float* __restrict__ A, const float* __restrict__ Wsg,
                   const float* __restrict__ soff,
                   float* __restrict__ scs, float* __restrict__ scd, int K) {
  __shared__ float ws[8][132];
  int tid = threadIdx.x;
  for (int idx = tid; idx < K * 8; idx += 256)
    ws[idx & 7][idx >> 3] = Wsg[idx];
  __syncthreads();
  int wave = tid >> 6, lane = tid & 63;
  int node = blockIdx.x * 4 + wave;
  if (node >= NNODES) return;
  float x1 = (lane < K) ? A[(size_t)node * K + lane] : 0.f;
  float x2 = (lane + 64 < K) ? A[(size_t)node * K + lane + 64] : 0.f;
  float acc[8];
  #pragma unroll
  for (int j = 0; j < 8; ++j) {
    float a = (lane < K) ? x1 * ws[j][lane] : 0.f;
    if (lane + 64 < K) a = fmaf(x2, ws[j][lane + 64], a);
    acc[j] = a;
  }
  #pragma unroll
  for (int d = 32; d >= 1; d >>= 1)
    #pragma unroll
    for (int j = 0; j < 8; ++j) acc[j] += __shfl_xor(acc[j], d);
  if (lane == 0) {
    float o0 = soff ? soff[0] : 0.f, o1 = soff ? soff[1] : 0.f;
    float o2 = soff ? soff[2] : 0.f, o3 = soff ? soff[3] : 0.f;
    float o4 = soff ? soff[4] : 0.f, o5 = soff ? soff[5] : 0.f;
    float o6 = soff ? soff[6] : 0.f, o7 = soff ? soff[7] : 0.f;
    *(float4*)(scs + (size_t)node * 4) = make_float4(acc[0] + o0, acc[1] + o1, acc[2] + o2, acc[3] + o3);
    *(float4*)(scd + (size_t)node * 4) = make_float4(acc[4] + o4, acc[5] + o5, acc[6] + o6, acc[7] + o7);
  }
}

// ---------------- fused GAT edge kernel: 2 nodes per wave (32 lanes each) ----------------
// Fast path requires deg<=32 for both nodes of the pair (P ~ 99.96%); rare big
// nodes take the 64-lane generic chunked path sequentially.
__global__ __launch_bounds__(256)
void gat_edge_kernel(const __half2* __restrict__ hproj_h,
                     const float* __restrict__ scs, const float* __restrict__ scd,
                     const int* __restrict__ row_start, const int* __restrict__ col_src,
                     const float* __restrict__ bias, float* __restrict__ hout) {
  __shared__ int src_sh[4][64];
  __shared__ __align__(16) float al_sh[4][256];
  int wave = threadIdx.x >> 6, lane = threadIdx.x & 63;
  int half = lane >> 5, l32 = lane & 31;
  int nodeBase = blockIdx.x * 8 + wave * 2;
  if (nodeBase >= NNODES) return;
  const uint4* hp4 = (const uint4*)hproj_h;   // 16 x uint4 per node row (128 fp16)

  int node = nodeBase + half;
  bool nvalid = node < NNODES;
  int s = 0, e = 0;
  if (nvalid) { s = row_start[node]; e = row_start[node + 1]; }
  int deg = e - s;
  int dmax = max(deg, __shfl_xor(deg, 32));

  if (dmax <= 32) {
    float4 sd = make_float4(0.f, 0.f, 0.f, 0.f);
    if (nvalid) sd = *(const float4*)(scd + (size_t)node * 4);
    bool valid = nvalid && (l32 < deg);
    int srcv = 0;
    float4 ss = make_float4(0.f, 0.f, 0.f, 0.f);
    if (valid) {
      srcv = col_src[s + l32];
      ss = *(const float4*)(scs + (size_t)srcv * 4);
    }
    float e0 = lrelu(ss.x + sd.x), e1 = lrelu(ss.y + sd.y);
    float e2 = lrelu(ss.z + sd.z), e3 = lrelu(ss.w + sd.w);
    float m0 = valid ? e0 : -INFINITY, m1 = valid ? e1 : -INFINITY;
    float m2 = valid ? e2 : -INFINITY, m3 = valid ? e3 : -INFINITY;
    #pragma unroll
    for (int d = 16; d >= 1; d >>= 1) {   // 5 levels: stays within 32-lane half
      m0 = fmaxf(m0, __shfl_xor(m0, d));
      m1 = fmaxf(m1, __shfl_xor(m1, d));
      m2 = fmaxf(m2, __shfl_xor(m2, d));
      m3 = fmaxf(m3, __shfl_xor(m3, d));
    }
    float a0 = valid ? __expf(e0 - m0) : 0.f;
    float a1 = valid ? __expf(e1 - m1) : 0.f;
    float a2 = valid ? __expf(e2 - m2) : 0.f;
    float a3 = valid ? __expf(e3 - m3) : 0.f;
    float d0 = a0, d1 = a1, d2 = a2, d3 = a3;
    #pragma unroll
    for (int d = 16; d >= 1; d >>= 1) {
      d0 += __shfl_xor(d0, d);
      d1 += __shfl_xor(d1, d);
      d2 += __shfl_xor(d2, d);
      d3 += __shfl_xor(d3, d);
    }
    src_sh[wave][lane] = srcv;
    *(float4*)&al_sh[wave][lane * 4] = make_float4(a0, a1, a2, a3);

    // heavy loop: per half, 2 edges/iter x 16 lanes (uint4 = 8 fp16 ch each)
    int g2 = l32 >> 4;         // edge-in-pair
    int r  = l32 & 15;         // payload slot: flat channels [8r,8r+8), head=r>>2
    int head = r >> 2;
    float acc[8] = {};
    int ng = (dmax + 1) >> 1;
    for (int jg = 0; jg < ng; ++jg) {
      int j = jg * 2 + g2;                 // 0..31
      int slot = half * 32 + j;
      int src = src_sh[wave][slot];
      float al = al_sh[wave][slot * 4 + head];
      uint4 p = hp4[(size_t)src * 16 + r];
      float2 f0 = __half22float2(*(__half2*)&p.x);
      float2 f1 = __half22float2(*(__half2*)&p.y);
      float2 f2 = __half22float2(*(__half2*)&p.z);
      float2 f3 = __half22float2(*(__half2*)&p.w);
      acc[0] = fmaf(al, f0.x, acc[0]); acc[1] = fmaf(al, f0.y, acc[1]);
      acc[2] = fmaf(al, f1.x, acc[2]); acc[3] = fmaf(al, f1.y, acc[3]);
      acc[4] = fmaf(al, f2.x, acc[4]); acc[5] = fmaf(al, f2.y, acc[5]);
      acc[6] = fmaf(al, f3.x, acc[6]); acc[7] = fmaf(al, f3.y, acc[7]);
    }
    float den = (head == 0) ? d0 : (head == 1) ? d1 : (head == 2) ? d2 : d3;
    float rd = 1.f / fmaxf(den, 1e-16f);
    #pragma unroll
    for (int k = 0; k < 8; ++k) acc[k] *= rd;
    // combine edge pair (xor 16), then head mean (xor 4, 8) - all within half
    #pragma unroll
    for (int k = 0; k < 8; ++k) acc[k] += __shfl_xor(acc[k], 16);
    #pragma unroll
    for (int k = 0; k < 8; ++k) acc[k] += __shfl_xor(acc[k], 4);
    #pragma unroll
    for (int k = 0; k < 8; ++k) acc[k] += __shfl_xor(acc[k], 8);
    if (nvalid && l32 < 4) {
      float o[8];
      #pragma unroll
      for (int k = 0; k < 8; ++k) {
        float v = acc[k] * 0.25f + bias[8 * l32 + k];
        o[k] = v > 0.f ? v : expm1f(v);
      }
      float* op = hout + (size_t)node * 32 + 8 * l32;
      *(float4*)op       = make_float4(o[0], o[1], o[2], o[3]);
      *(float4*)(op + 4) = make_float4(o[4], o[5], o[6], o[7]);
    }
  } else {
    // generic 64-lane chunked path, nodes of the pair processed sequentially
    for (int nn = 0; nn < 2; ++nn) {
      int nd = nodeBase + nn;
      if (nd >= NNODES) break;
      int s2 = row_start[nd], e2 = row_start[nd + 1];
      float4 sd = *(const float4*)(scd + (size_t)nd * 4);
      float m0 = -INFINITY, m1 = -INFINITY, m2 = -INFINITY, m3 = -INFINITY;
      for (int i = s2 + lane; i < e2; i += 64) {
        int src = col_src[i];
        float4 ss = *(const float4*)(scs + (size_t)src * 4);
        m0 = fmaxf(m0, lrelu(ss.x + sd.x));
        m1 = fmaxf(m1, lrelu(ss.y + sd.y));
        m2 = fmaxf(m2, lrelu(ss.z + sd.z));
        m3 = fmaxf(m3, lrelu(ss.w + sd.w));
      }
      #pragma unroll
      for (int d = 32; d >= 1; d >>= 1) {
        m0 = fmaxf(m0, __shfl_xor(m0, d));
        m1 = fmaxf(m1, __shfl_xor(m1, d));
        m2 = fmaxf(m2, __shfl_xor(m2, d));
        m3 = fmaxf(m3, __shfl_xor(m3, d));
      }
      int g = lane >> 4, r = lane & 15, head = r >> 2;
      float den0 = 0, den1 = 0, den2 = 0, den3 = 0;
      float acc[8] = {};
      for (int base = s2; base < e2; base += 64) {
        int i = base + lane;
        bool valid = i < e2;
        int srcv = 0;
        float a0 = 0, a1 = 0, a2 = 0, a3 = 0;
        if (valid) {
          srcv = col_src[i];
          float4 ss = *(const float4*)(scs + (size_t)srcv * 4);
          a0 = __expf(lrelu(ss.x + sd.x) - m0);
          a1 = __expf(lrelu(ss.y + sd.y) - m1);
          a2 = __expf(lrelu(ss.z + sd.z) - m2);
          a3 = __expf(lrelu(ss.w + sd.w) - m3);
          den0 += a0; den1 += a1; den2 += a2; den3 += a3;
        }
        src_sh[wave][lane] = srcv;
        *(float4*)&al_sh[wave][lane * 4] = make_float4(a0, a1, a2, a3);
        int cnt = min(64, e2 - base);
        int ngc = (cnt + 3) >> 2;
        for (int jg = 0; jg < ngc; ++jg) {
          int j = jg * 4 + g;
          int src = src_sh[wave][j];
          float al = al_sh[wave][j * 4 + head];
          uint4 p = hp4[(size_t)src * 16 + r];
          float2 f0 = __half22float2(*(__half2*)&p.x);
          float2 f1 = __half22float2(*(__half2*)&p.y);
          float2 f2 = __half22float2(*(__half2*)&p.z);
          float2 f3 = __half22float2(*(__half2*)&p.w);
          acc[0] = fmaf(al, f0.x, acc[0]); acc[1] = fmaf(al, f0.y, acc[1]);
          acc[2] = fmaf(al, f1.x, acc[2]); acc[3] = fmaf(al, f1.y, acc[3]);
          acc[4] = fmaf(al, f2.x, acc[4]); acc[5] = fmaf(al, f2.y, acc[5]);
          acc[6] = fmaf(al, f3.x, acc[6]); acc[7] = fmaf(al, f3.y, acc[7]);
        }
      }
      #pragma unroll
      for (int d = 32; d >= 1; d >>= 1) {
        den0 += __shfl_xor(den0, d);
        den1 += __shfl_xor(den1, d);
        den2 += __shfl_xor(den2, d);
        den3 += __shfl_xor(den3, d);
      }
      float den = (head == 0) ? den0 : (head == 1) ? den1 : (head == 2) ? den2 : den3;
      float rd = 1.f / fmaxf(den, 1e-16f);
      #pragma unroll
      for (int k = 0; k < 8; ++k) acc[k] *= rd;
      #pragma unroll
      for (int d = 4; d <= 32; d <<= 1) {
        #pragma unroll
        for (int k = 0; k < 8; ++k) acc[k] += __shfl_xor(acc[k], d);
      }
      if (lane < 4) {
        float o[8];
        #pragma unroll
        for (int k = 0; k < 8; ++k) {
          float v = acc[k] * 0.25f + bias[8 * lane + k];
          o[k] = v > 0.f ? v : expm1f(v);
        }
        float* op = hout + (size_t)nd * 32 + 8 * lane;
        *(float4*)op       = make_float4(o[0], o[1], o[2], o[3]);
        *(float4*)(op + 4) = make_float4(o[4], o[5], o[6], o[7]);
      }
    }
  }
}

// ---------------- hierarchical global mean pool ----------------
#define POOL_BLOCKS 128
__global__ __launch_bounds__(256)
void pool_kernel(const float* __restrict__ h, const int* __restrict__ batch,
                 float* __restrict__ pooled, float* __restrict__ cnt) {
  __shared__ float acc[NGRAPH][HIDC];
  __shared__ float ccnt[NGRAPH];
  int tid = threadIdx.x;
  const int chunk = (NNODES + POOL_BLOCKS - 1) / POOL_BLOCKS;
  int n0 = blockIdx.x * chunk;
  int n1 = min(n0 + chunk, NNODES);
  if (n0 >= NNODES) return;
  int g0 = batch[n0], g1 = batch[n1 - 1];
  int rows = g1 - g0 + 1;
  for (int idx = tid; idx < rows * HIDC; idx += 256)
    acc[g0 + (idx >> 5)][idx & 31] = 0.f;
  for (int g = tid; g < rows; g += 256) ccnt[g0 + g] = 0.f;
  __syncthreads();
  int c = tid & 31;
  for (int node = n0 + (tid >> 5); node < n1; node += 8) {
    int g = batch[node];
    atomicAdd(&acc[g][c], h[(size_t)node * HIDC + c]);
    if (c == 0) atomicAdd(&ccnt[g], 1.f);
  }
  __syncthreads();
  for (int idx = tid; idx < rows * HIDC; idx += 256) {
    int g = g0 + (idx >> 5), cc = idx & 31;
    atomicAdd(&pooled[g * HIDC + cc], acc[g][cc]);
  }
  for (int g = tid; g < rows; g += 256) atomicAdd(&cnt[g0 + g], ccnt[g0 + g]);
}

__global__ void final_kernel(const float* __restrict__ pooled, const float* __restrict__ cnt,
                             const float* __restrict__ w, const float* __restrict__ b,
                             float* __restrict__ out) {
  int t = threadIdx.x;
  if (t >= NGRAPH * NCLS) return;
  int g = t / NCLS, j = t - g * NCLS;
  float inv = 1.f / fmaxf(cnt[g], 1.f);
  float acc = 0.f;
  #pragma unroll
  for (int c = 0; c < HIDC; ++c)
    acc = fmaf(pooled[g * HIDC + c], w[c * NCLS + j], acc);
  out[t] = acc * inv + b[j];
}

extern "C" void kernel_launch(void* const* d_in, const int* in_sizes, int n_in,
                              void* d_out, int out_size, void* d_ws, size_t ws_size,
                              hipStream_t stream) {
  const float* x      = (const float*)d_in[0];
  const int*   ei     = (const int*)d_in[1];
  const int*   batch  = (const int*)d_in[2];
  const float* enc1_w = (const float*)d_in[3];
  const float* enc1_b = (const float*)d_in[4];
  const float* enc2_w = (const float*)d_in[5];
  const float* enc2_b = (const float*)d_in[6];
  const float* lin1_w = (const float*)d_in[7];
  const float* lin1_b = (const float*)d_in[8];
  const float* gw[4]  = {(const float*)d_in[9],  (const float*)d_in[13], (const float*)d_in[17], (const float*)d_in[21]};
  const float* gas[4] = {(const float*)d_in[10], (const float*)d_in[14], (const float*)d_in[18], (const float*)d_in[22]};
  const float* gad[4] = {(const float*)d_in[11], (const float*)d_in[15], (const float*)d_in[19], (const float*)d_in[23]};
  const float* gb[4]  = {(const float*)d_in[12], (const float*)d_in[16], (const float*)d_in[20], (const float*)d_in[24]};
  float* out = (float*)d_out;

  __half* hproj_h = (__half*)d_ws;                          // N*128 fp16
  float*  fws     = (float*)(hproj_h + (size_t)NNODES * 128);
  float* hsmall = fws;                                      // N*32
  float* scs    = hsmall + (size_t)NNODES * 32;             // N*4
  float* scd    = scs    + (size_t)NNODES * 4;              // N*4
  float* pooled = scd    + (size_t)NNODES * 4;              // 64*32
  float* cnt    = pooled + NGRAPH * HIDC;                   // 64
  float* T1     = cnt + NGRAPH;                             // 128*256
  float* Wc     = T1 + 128 * 256;                           // 128*128
  float* b2c    = Wc + 128 * 128;                           // 256
  float* bc     = b2c + 256;                                // 128
  float* soff1  = bc + 128;                                 // 8
  float* Ws1    = soff1 + 8;                                // 128*8
  float* Ws2    = Ws1 + 128 * 8;                            // 32*8
  float* Ws3    = Ws2 + 32 * 8;
  float* Ws4    = Ws3 + 32 * 8;
  int* deg       = (int*)(Ws4 + 32 * 8);                    // N
  int* row_start = deg + NNODES;                            // N+1
  int* col_src   = row_start + NNODES + 1;                  // ETOT
  int* bsum      = col_src + ETOT;                          // 196
  int* boff      = bsum + SCAN_BLOCKS;                      // 196

  // --- weight composition (proper tiled GEMMs) ---
  gemm_f32<<<dim3(2, 4), 256, 0, stream>>>(enc1_w, enc2_w, nullptr, T1, 128, 128, 256);
  gemm_f32<<<dim3(2, 2), 256, 0, stream>>>(T1, gw[0], nullptr, Wc, 128, 256, 128);
  vecmat_kernel<<<1, 256, 0, stream>>>(enc1_b, enc2_w, enc2_b, b2c, 128, 256);
  vecmat_kernel<<<1, 256, 0, stream>>>(b2c, gw[0], nullptr, bc, 256, 128);
  score_fold_kernel<<<4, 256, 0, stream>>>(Wc, gas[0], gad[0], Ws1, 128);
  score_fold_kernel<<<1, 256, 0, stream>>>(bc, gas[0], gad[0], soff1, 1);
  score_fold_kernel<<<1, 256, 0, stream>>>(gw[1], gas[1], gad[1], Ws2, 32);
  score_fold_kernel<<<1, 256, 0, stream>>>(gw[2], gas[2], gad[2], Ws3, 32);
  score_fold_kernel<<<1, 256, 0, stream>>>(gw[3], gas[3], gad[3], Ws4, 32);

  // --- CSR build (parallel scan) ---
  hipMemsetAsync(deg, 0, NNODES * sizeof(int), stream);
  hist_kernel<<<(ETOT + 255) / 256, 256, 0, stream>>>(ei, deg);
  scan_block_kernel<<<SCAN_BLOCKS, 256, 0, stream>>>(deg, row_start, bsum);
  scan_sums_kernel<<<1, 256, 0, stream>>>(bsum, boff);
  scan_add_kernel<<<SCAN_BLOCKS, 256, 0, stream>>>(boff, row_start);
  hipMemsetAsync(deg, 0, NNODES * sizeof(int), stream);
  scatter_kernel<<<(ETOT + 255) / 256, 256, 0, stream>>>(ei, row_start, deg, col_src);

  dim3 gproj((NNODES + 63) / 64, 2);
  int nodeblocks = (NNODES + 3) / 4;
  int edgeblocks = (NNODES + 7) / 8;

  // --- layer 1 (composite: enc1+enc2+g1 projection in one GEMM) ---
  gemm_h16<<<gproj, 256, 0, stream>>>(x, Wc, bc, hproj_h, NNODES, 128);
  scores_direct<<<nodeblocks, 256, 0, stream>>>(x, Ws1, soff1, scs, scd, 128);
  gat_edge_kernel<<<edgeblocks, 256, 0, stream>>>((const __half2*)hproj_h, scs, scd, row_start, col_src, gb[0], hsmall);

  // --- layers 2..4 ---
  const float* WsL[4] = {Ws1, Ws2, Ws3, Ws4};
  for (int L = 1; L < 4; ++L) {
    gemm_h16<<<gproj, 256, 0, stream>>>(hsmall, gw[L], nullptr, hproj_h, NNODES, 32);
    scores_direct<<<nodeblocks, 256, 0, stream>>>(hsmall, WsL[L], nullptr, scs, scd, 32);
    gat_edge_kernel<<<edgeblocks, 256, 0, stream>>>((const __half2*)hproj_h, scs, scd, row_start, col_src, gb[L], hsmall);
  }

  // --- pooling + classifier ---
  hipMemsetAsync(pooled, 0, (NGRAPH * HIDC + NGRAPH) * sizeof(float), stream);
  pool_kernel<<<POOL_BLOCKS, 256, 0, stream>>>(hsmall, batch, pooled, cnt);
  final_kernel<<<1, 640, 0, stream>>>(pooled, cnt, lin1_w, lin1_b, out);
}

// Round 8
// 590.515 us; speedup vs baseline: 1.3921x; 1.1561x over previous
//
#include <hip/hip_runtime.h>
#include <hip/hip_fp16.h>
#include <math.h>

#define NNODES 50000
#define NEDGES 800000
#define ETOT   (NEDGES + NNODES)
#define HIDC   32
#define NGRAPH 64
#define NCLS   10
#define SLOPE  0.2f
#define SCAN_BLOCKS ((NNODES + 255) / 256)   // 196

__device__ __forceinline__ float lrelu(float v) { return v > 0.f ? v : SLOPE * v; }

// ---------------- CSR build (by dst), includes self loops ----------------
__global__ void hist_kernel(const int* __restrict__ ei, int* __restrict__ deg) {
  int e = blockIdx.x * 256 + threadIdx.x;
  if (e >= ETOT) return;
  int d = (e < NEDGES) ? ei[NEDGES + e] : (e - NEDGES);
  atomicAdd(&deg[d], 1);
}

__global__ __launch_bounds__(256)
void scan_block_kernel(const int* __restrict__ deg, int* __restrict__ row_start,
                       int* __restrict__ bsum) {
  __shared__ int wsum[4];
  int i = blockIdx.x * 256 + threadIdx.x;
  int v = (i < NNODES) ? deg[i] : 0;
  int lane = threadIdx.x & 63, w = threadIdx.x >> 6;
  int x = v;
  #pragma unroll
  for (int d = 1; d < 64; d <<= 1) {
    int y = __shfl_up(x, d);
    if (lane >= d) x += y;
  }
  if (lane == 63) wsum[w] = x;
  __syncthreads();
  int woff = 0;
  #pragma unroll
  for (int j = 0; j < 4; ++j) if (j < w) woff += wsum[j];
  int incl = x + woff;
  if (i < NNODES) row_start[i] = incl - v;
  if (threadIdx.x == 255) bsum[blockIdx.x] = incl;
}

__global__ __launch_bounds__(256)
void scan_sums_kernel(const int* __restrict__ bsum, int* __restrict__ boff) {
  __shared__ int wsum[4];
  int tid = threadIdx.x;
  int v = (tid < SCAN_BLOCKS) ? bsum[tid] : 0;
  int lane = tid & 63, w = tid >> 6;
  int x = v;
  #pragma unroll
  for (int d = 1; d < 64; d <<= 1) {
    int y = __shfl_up(x, d);
    if (lane >= d) x += y;
  }
  if (lane == 63) wsum[w] = x;
  __syncthreads();
  int woff = 0;
  #pragma unroll
  for (int j = 0; j < 4; ++j) if (j < w) woff += wsum[j];
  if (tid < SCAN_BLOCKS) boff[tid] = (x + woff) - v;
}

__global__ __launch_bounds__(256)
void scan_add_kernel(const int* __restrict__ boff, int* __restrict__ row_start) {
  int i = blockIdx.x * 256 + threadIdx.x;
  if (i < NNODES) row_start[i] += boff[blockIdx.x];
  if (i == 0) row_start[NNODES] = ETOT;
}

__global__ void scatter_kernel(const int* __restrict__ ei, const int* __restrict__ row_start,
                               int* __restrict__ cursor, int* __restrict__ col_src) {
  int e = blockIdx.x * 256 + threadIdx.x;
  if (e >= ETOT) return;
  int s, d;
  if (e < NEDGES) { s = ei[e]; d = ei[NEDGES + e]; }
  else { s = d = e - NEDGES; }
  int pos = atomicAdd(&cursor[d], 1);
  col_src[row_start[d] + pos] = s;
}

// ---------------- fp32 tiled GEMM (fp32 out) ----------------
__global__ __launch_bounds__(256)
void gemm_f32(const float* __restrict__ A, const float* __restrict__ B,
              const float* __restrict__ bias, float* __restrict__ C,
              int M, int K, int N) {
  __shared__ float As[32][68];
  __shared__ float Bs[32][68];
  int row0 = blockIdx.x * 64, col0 = blockIdx.y * 64;
  int tid = threadIdx.x;
  int tx = tid & 15, ty = tid >> 4;
  float acc[4][4] = {};
  for (int k0 = 0; k0 < K; k0 += 32) {
    #pragma unroll
    for (int i = 0; i < 8; ++i) {
      int idx = tid + i * 256;
      int r = idx >> 5, c = idx & 31;
      int gr = row0 + r;
      As[c][r] = (gr < M) ? A[(size_t)gr * K + k0 + c] : 0.f;
    }
    #pragma unroll
    for (int i = 0; i < 8; ++i) {
      int idx = tid + i * 256;
      int r = idx >> 6, c = idx & 63;
      Bs[r][c] = B[(size_t)(k0 + r) * N + col0 + c];
    }
    __syncthreads();
    #pragma unroll
    for (int k = 0; k < 32; ++k) {
      float a4[4], b4[4];
      #pragma unroll
      for (int i = 0; i < 4; ++i) a4[i] = As[k][ty * 4 + i];
      #pragma unroll
      for (int j = 0; j < 4; ++j) b4[j] = Bs[k][tx * 4 + j];
      #pragma unroll
      for (int i = 0; i < 4; ++i)
        #pragma unroll
        for (int j = 0; j < 4; ++j)
          acc[i][j] = fmaf(a4[i], b4[j], acc[i][j]);
    }
    __syncthreads();
  }
  #pragma unroll
  for (int i = 0; i < 4; ++i) {
    int gr = row0 + ty * 4 + i;
    if (gr >= M) continue;
    #pragma unroll
    for (int j = 0; j < 4; ++j) {
      int gc = col0 + tx * 4 + j;
      C[(size_t)gr * N + gc] = acc[i][j] + (bias ? bias[gc] : 0.f);
    }
  }
}

// ---------------- wave-per-output vecmat: out[j] = v @ W[:,j] + bias[j] ----------------
__global__ __launch_bounds__(256)
void vecmat_fast(const float* __restrict__ v, const float* __restrict__ W,
                 const float* __restrict__ bias, float* __restrict__ out,
                 int K, int N) {
  int wave = threadIdx.x >> 6, lane = threadIdx.x & 63;
  int j = blockIdx.x * 4 + wave;
  if (j >= N) return;
  float acc = 0.f;
  for (int k = lane; k < K; k += 64)
    acc = fmaf(v[k], W[(size_t)k * N + j], acc);
  #pragma unroll
  for (int d = 32; d >= 1; d >>= 1) acc += __shfl_xor(acc, d);
  if (lane == 0) out[j] = acc + (bias ? bias[j] : 0.f);
}

// Ws[r][j] = sum_c W[r, h*32+c] * a[h][c],  h=j&3, a = as_ (j<4) or ad_ (j>=4)
__global__ void score_fold_kernel(const float* __restrict__ W, const float* __restrict__ as_,
                                  const float* __restrict__ ad_, float* __restrict__ Ws, int din) {
  int t = blockIdx.x * 256 + threadIdx.x;
  if (t >= din * 8) return;
  int r = t >> 3, j = t & 7, h = j & 3;
  const float* a = (j < 4) ? as_ : ad_;
  float s = 0.f;
  for (int c = 0; c < 32; ++c) s = fmaf(W[r * 128 + h * 32 + c], a[h * 32 + c], s);
  Ws[t] = s;
}

// ---------------- fp32 tiled GEMM -> fp16 output [M,128] ----------------
__global__ __launch_bounds__(256)
void gemm_h16(const float* __restrict__ A, const float* __restrict__ B,
              const float* __restrict__ bias, __half* __restrict__ Ch,
              int M, int K) {
  __shared__ float As[32][68];
  __shared__ float Bs[32][68];
  int row0 = blockIdx.x * 64, col0 = blockIdx.y * 64;
  int tid = threadIdx.x;
  int tx = tid & 15, ty = tid >> 4;
  float acc[4][4] = {};
  for (int k0 = 0; k0 < K; k0 += 32) {
    #pragma unroll
    for (int i = 0; i < 8; ++i) {
      int idx = tid + i * 256;
      int r = idx >> 5, c = idx & 31;
      int gr = row0 + r;
      As[c][r] = (gr < M && (k0 + c) < K) ? A[(size_t)gr * K + k0 + c] : 0.f;
    }
    #pragma unroll
    for (int i = 0; i < 8; ++i) {
      int idx = tid + i * 256;
      int r = idx >> 6, c = idx & 63;
      Bs[r][c] = ((k0 + r) < K) ? B[(size_t)(k0 + r) * 128 + col0 + c] : 0.f;
    }
    __syncthreads();
    #pragma unroll
    for (int k = 0; k < 32; ++k) {
      float a4[4], b4[4];
      #pragma unroll
      for (int i = 0; i < 4; ++i) a4[i] = As[k][ty * 4 + i];
      #pragma unroll
      for (int j = 0; j < 4; ++j) b4[j] = Bs[k][tx * 4 + j];
      #pragma unroll
      for (int i = 0; i < 4; ++i)
        #pragma unroll
        for (int j = 0; j < 4; ++j)
          acc[i][j] = fmaf(a4[i], b4[j], acc[i][j]);
    }
    __syncthreads();
  }
  #pragma unroll
  for (int i = 0; i < 4; ++i) {
    int gr = row0 + ty * 4 + i;
    if (gr >= M) continue;
    int gc0 = col0 + tx * 4;
    float v0 = acc[i][0] + (bias ? bias[gc0]     : 0.f);
    float v1 = acc[i][1] + (bias ? bias[gc0 + 1] : 0.f);
    float v2 = acc[i][2] + (bias ? bias[gc0 + 2] : 0.f);
    float v3 = acc[i][3] + (bias ? bias[gc0 + 3] : 0.f);
    __half2* hp = (__half2*)(Ch + (size_t)gr * 128 + gc0);
    hp[0] = __floats2half2_rn(v0, v1);
    hp[1] = __floats2half2_rn(v2, v3);
  }
}

// ---------------- direct per-node scores: sc = A @ Ws (+soff), 8 cols ----------------
__global__ __launch_bounds__(256)
void scores_direct(const float* __restrict__ A, const float* __restrict__ Wsg,
                   const float* __restrict__ soff,
                   float* __restrict__ scs, float* __restrict__ scd, int K) {
  __shared__ float ws[8][132];
  int tid = threadIdx.x;
  for (int idx = tid; idx < K * 8; idx += 256)
    ws[idx & 7][idx >> 3] = Wsg[idx];
  __syncthreads();
  int wave = tid >> 6, lane = tid & 63;
  int node = blockIdx.x * 4 + wave;
  if (node >= NNODES) return;
  float x1 = (lane < K) ? A[(size_t)node * K + lane] : 0.f;
  float x2 = (lane + 64 < K) ? A[(size_t)node * K + lane + 64] : 0.f;
  float acc[8];
  #pragma unroll
  for (int j = 0; j < 8; ++j) {
    float a = (lane < K) ? x1 * ws[j][lane] : 0.f;
    if (lane + 64 < K) a = fmaf(x2, ws[j][lane + 64], a);
    acc[j] = a;
  }
  #pragma unroll
  for (int d = 32; d >= 1; d >>= 1)
    #pragma unroll
    for (int j = 0; j < 8; ++j) acc[j] += __shfl_xor(acc[j], d);
  if (lane == 0) {
    float o0 = soff ? soff[0] : 0.f, o1 = soff ? soff[1] : 0.f;
    float o2 = soff ? soff[2] : 0.f, o3 = soff ? soff[3] : 0.f;
    float o4 = soff ? soff[4] : 0.f, o5 = soff ? soff[5] : 0.f;
    float o6 = soff ? soff[6] : 0.f, o7 = soff ? soff[7] : 0.f;
    *(float4*)(scs + (size_t)node * 4) = make_float4(acc[0] + o0, acc[1] + o1, acc[2] + o2, acc[3] + o3);
    *(float4*)(scd + (size_t)node * 4) = make_float4(acc[4] + o4, acc[5] + o5, acc[6] + o6, acc[7] + o7);
  }
}

// ---------------- fused GAT edge kernel: 2 nodes per wave (32 lanes each) ----------------
__global__ __launch_bounds__(256)
void gat_edge_kernel(const __half2* __restrict__ hproj_h,
                     const float* __restrict__ scs, const float* __restrict__ scd,
                     const int* __restrict__ row_start, const int* __restrict__ col_src,
                     const float* __restrict__ bias, float* __restrict__ hout) {
  __shared__ int src_sh[4][64];
  __shared__ __align__(16) float al_sh[4][256];
  int wave = threadIdx.x >> 6, lane = threadIdx.x & 63;
  int half = lane >> 5, l32 = lane & 31;
  int nodeBase = blockIdx.x * 8 + wave * 2;
  if (nodeBase >= NNODES) return;
  const uint4* hp4 = (const uint4*)hproj_h;

  int node = nodeBase + half;
  bool nvalid = node < NNODES;
  int s = 0, e = 0;
  if (nvalid) { s = row_start[node]; e = row_start[node + 1]; }
  int deg = e - s;
  int dmax = max(deg, __shfl_xor(deg, 32));

  if (dmax <= 32) {
    float4 sd = make_float4(0.f, 0.f, 0.f, 0.f);
    if (nvalid) sd = *(const float4*)(scd + (size_t)node * 4);
    bool valid = nvalid && (l32 < deg);
    int srcv = 0;
    float4 ss = make_float4(0.f, 0.f, 0.f, 0.f);
    if (valid) {
      srcv = col_src[s + l32];
      ss = *(const float4*)(scs + (size_t)srcv * 4);
    }
    float e0 = lrelu(ss.x + sd.x), e1 = lrelu(ss.y + sd.y);
    float e2 = lrelu(ss.z + sd.z), e3 = lrelu(ss.w + sd.w);
    float m0 = valid ? e0 : -INFINITY, m1 = valid ? e1 : -INFINITY;
    float m2 = valid ? e2 : -INFINITY, m3 = valid ? e3 : -INFINITY;
    #pragma unroll
    for (int d = 16; d >= 1; d >>= 1) {
      m0 = fmaxf(m0, __shfl_xor(m0, d));
      m1 = fmaxf(m1, __shfl_xor(m1, d));
      m2 = fmaxf(m2, __shfl_xor(m2, d));
      m3 = fmaxf(m3, __shfl_xor(m3, d));
    }
    float a0 = valid ? __expf(e0 - m0) : 0.f;
    float a1 = valid ? __expf(e1 - m1) : 0.f;
    float a2 = valid ? __expf(e2 - m2) : 0.f;
    float a3 = valid ? __expf(e3 - m3) : 0.f;
    float d0 = a0, d1 = a1, d2 = a2, d3 = a3;
    #pragma unroll
    for (int d = 16; d >= 1; d >>= 1) {
      d0 += __shfl_xor(d0, d);
      d1 += __shfl_xor(d1, d);
      d2 += __shfl_xor(d2, d);
      d3 += __shfl_xor(d3, d);
    }
    src_sh[wave][lane] = srcv;
    *(float4*)&al_sh[wave][lane * 4] = make_float4(a0, a1, a2, a3);

    int g2 = l32 >> 4;
    int r  = l32 & 15;
    int head = r >> 2;
    float acc[8] = {};
    int ng = (dmax + 1) >> 1;
    for (int jg = 0; jg < ng; ++jg) {
      int j = jg * 2 + g2;
      int slot = half * 32 + j;
      int src = src_sh[wave][slot];
      float al = al_sh[wave][slot * 4 + head];
      uint4 p = hp4[(size_t)src * 16 + r];
      float2 f0 = __half22float2(*(__half2*)&p.x);
      float2 f1 = __half22float2(*(__half2*)&p.y);
      float2 f2 = __half22float2(*(__half2*)&p.z);
      float2 f3 = __half22float2(*(__half2*)&p.w);
      acc[0] = fmaf(al, f0.x, acc[0]); acc[1] = fmaf(al, f0.y, acc[1]);
      acc[2] = fmaf(al, f1.x, acc[2]); acc[3] = fmaf(al, f1.y, acc[3]);
      acc[4] = fmaf(al, f2.x, acc[4]); acc[5] = fmaf(al, f2.y, acc[5]);
      acc[6] = fmaf(al, f3.x, acc[6]); acc[7] = fmaf(al, f3.y, acc[7]);
    }
    float den = (head == 0) ? d0 : (head == 1) ? d1 : (head == 2) ? d2 : d3;
    float rd = 1.f / fmaxf(den, 1e-16f);
    #pragma unroll
    for (int k = 0; k < 8; ++k) acc[k] *= rd;
    #pragma unroll
    for (int k = 0; k < 8; ++k) acc[k] += __shfl_xor(acc[k], 16);
    #pragma unroll
    for (int k = 0; k < 8; ++k) acc[k] += __shfl_xor(acc[k], 4);
    #pragma unroll
    for (int k = 0; k < 8; ++k) acc[k] += __shfl_xor(acc[k], 8);
    if (nvalid && l32 < 4) {
      float o[8];
      #pragma unroll
      for (int k = 0; k < 8; ++k) {
        float v = acc[k] * 0.25f + bias[8 * l32 + k];
        o[k] = v > 0.f ? v : expm1f(v);
      }
      float* op = hout + (size_t)node * 32 + 8 * l32;
      *(float4*)op       = make_float4(o[0], o[1], o[2], o[3]);
      *(float4*)(op + 4) = make_float4(o[4], o[5], o[6], o[7]);
    }
  } else {
    for (int nn = 0; nn < 2; ++nn) {
      int nd = nodeBase + nn;
      if (nd >= NNODES) break;
      int s2 = row_start[nd], e2 = row_start[nd + 1];
      float4 sd = *(const float4*)(scd + (size_t)nd * 4);
      float m0 = -INFINITY, m1 = -INFINITY, m2 = -INFINITY, m3 = -INFINITY;
      for (int i = s2 + lane; i < e2; i += 64) {
        int src = col_src[i];
        float4 ss = *(const float4*)(scs + (size_t)src * 4);
        m0 = fmaxf(m0, lrelu(ss.x + sd.x));
        m1 = fmaxf(m1, lrelu(ss.y + sd.y));
        m2 = fmaxf(m2, lrelu(ss.z + sd.z));
        m3 = fmaxf(m3, lrelu(ss.w + sd.w));
      }
      #pragma unroll
      for (int d = 32; d >= 1; d >>= 1) {
        m0 = fmaxf(m0, __shfl_xor(m0, d));
        m1 = fmaxf(m1, __shfl_xor(m1, d));
        m2 = fmaxf(m2, __shfl_xor(m2, d));
        m3 = fmaxf(m3, __shfl_xor(m3, d));
      }
      int g = lane >> 4, r = lane & 15, head = r >> 2;
      float den0 = 0, den1 = 0, den2 = 0, den3 = 0;
      float acc[8] = {};
      for (int base = s2; base < e2; base += 64) {
        int i = base + lane;
        bool valid = i < e2;
        int srcv = 0;
        float a0 = 0, a1 = 0, a2 = 0, a3 = 0;
        if (valid) {
          srcv = col_src[i];
          float4 ss = *(const float4*)(scs + (size_t)srcv * 4);
          a0 = __expf(lrelu(ss.x + sd.x) - m0);
          a1 = __expf(lrelu(ss.y + sd.y) - m1);
          a2 = __expf(lrelu(ss.z + sd.z) - m2);
          a3 = __expf(lrelu(ss.w + sd.w) - m3);
          den0 += a0; den1 += a1; den2 += a2; den3 += a3;
        }
        src_sh[wave][lane] = srcv;
        *(float4*)&al_sh[wave][lane * 4] = make_float4(a0, a1, a2, a3);
        int cnt = min(64, e2 - base);
        int ngc = (cnt + 3) >> 2;
        for (int jg = 0; jg < ngc; ++jg) {
          int j = jg * 4 + g;
          int src = src_sh[wave][j];
          float al = al_sh[wave][j * 4 + head];
          uint4 p = hp4[(size_t)src * 16 + r];
          float2 f0 = __half22float2(*(__half2*)&p.x);
          float2 f1 = __half22float2(*(__half2*)&p.y);
          float2 f2 = __half22float2(*(__half2*)&p.z);
          float2 f3 = __half22float2(*(__half2*)&p.w);
          acc[0] = fmaf(al, f0.x, acc[0]); acc[1] = fmaf(al, f0.y, acc[1]);
          acc[2] = fmaf(al, f1.x, acc[2]); acc[3] = fmaf(al, f1.y, acc[3]);
          acc[4] = fmaf(al, f2.x, acc[4]); acc[5] = fmaf(al, f2.y, acc[5]);
          acc[6] = fmaf(al, f3.x, acc[6]); acc[7] = fmaf(al, f3.y, acc[7]);
        }
      }
      #pragma unroll
      for (int d = 32; d >= 1; d >>= 1) {
        den0 += __shfl_xor(den0, d);
        den1 += __shfl_xor(den1, d);
        den2 += __shfl_xor(den2, d);
        den3 += __shfl_xor(den3, d);
      }
      float den = (head == 0) ? den0 : (head == 1) ? den1 : (head == 2) ? den2 : den3;
      float rd = 1.f / fmaxf(den, 1e-16f);
      #pragma unroll
      for (int k = 0; k < 8; ++k) acc[k] *= rd;
      #pragma unroll
      for (int d = 4; d <= 32; d <<= 1) {
        #pragma unroll
        for (int k = 0; k < 8; ++k) acc[k] += __shfl_xor(acc[k], d);
      }
      if (lane < 4) {
        float o[8];
        #pragma unroll
        for (int k = 0; k < 8; ++k) {
          float v = acc[k] * 0.25f + bias[8 * lane + k];
          o[k] = v > 0.f ? v : expm1f(v);
        }
        float* op = hout + (size_t)nd * 32 + 8 * lane;
        *(float4*)op       = make_float4(o[0], o[1], o[2], o[3]);
        *(float4*)(op + 4) = make_float4(o[4], o[5], o[6], o[7]);
      }
    }
  }
}

// ---------------- hierarchical global mean pool ----------------
#define POOL_BLOCKS 128
__global__ __launch_bounds__(256)
void pool_kernel(const float* __restrict__ h, const int* __restrict__ batch,
                 float* __restrict__ pooled, float* __restrict__ cnt) {
  __shared__ float acc[NGRAPH][HIDC];
  __shared__ float ccnt[NGRAPH];
  int tid = threadIdx.x;
  const int chunk = (NNODES + POOL_BLOCKS - 1) / POOL_BLOCKS;
  int n0 = blockIdx.x * chunk;
  int n1 = min(n0 + chunk, NNODES);
  if (n0 >= NNODES) return;
  int g0 = batch[n0], g1 = batch[n1 - 1];
  int rows = g1 - g0 + 1;
  for (int idx = tid; idx < rows * HIDC; idx += 256)
    acc[g0 + (idx >> 5)][idx & 31] = 0.f;
  for (int g = tid; g < rows; g += 256) ccnt[g0 + g] = 0.f;
  __syncthreads();
  int c = tid & 31;
  for (int node = n0 + (tid >> 5); node < n1; node += 8) {
    int g = batch[node];
    atomicAdd(&acc[g][c], h[(size_t)node * HIDC + c]);
    if (c == 0) atomicAdd(&ccnt[g], 1.f);
  }
  __syncthreads();
  for (int idx = tid; idx < rows * HIDC; idx += 256) {
    int g = g0 + (idx >> 5), cc = idx & 31;
    atomicAdd(&pooled[g * HIDC + cc], acc[g][cc]);
  }
  for (int g = tid; g < rows; g += 256) atomicAdd(&cnt[g0 + g], ccnt[g0 + g]);
}

__global__ void final_kernel(const float* __restrict__ pooled, const float* __restrict__ cnt,
                             const float* __restrict__ w, const float* __restrict__ b,
                             float* __restrict__ out) {
  int t = threadIdx.x;
  if (t >= NGRAPH * NCLS) return;
  int g = t / NCLS, j = t - g * NCLS;
  float inv = 1.f / fmaxf(cnt[g], 1.f);
  float acc = 0.f;
  #pragma unroll
  for (int c = 0; c < HIDC; ++c)
    acc = fmaf(pooled[g * HIDC + c], w[c * NCLS + j], acc);
  out[t] = acc * inv + b[j];
}

extern "C" void kernel_launch(void* const* d_in, const int* in_sizes, int n_in,
                              void* d_out, int out_size, void* d_ws, size_t ws_size,
                              hipStream_t stream) {
  const float* x      = (const float*)d_in[0];
  const int*   ei     = (const int*)d_in[1];
  const int*   batch  = (const int*)d_in[2];
  const float* enc1_w = (const float*)d_in[3];
  const float* enc1_b = (const float*)d_in[4];
  const float* enc2_w = (const float*)d_in[5];
  const float* enc2_b = (const float*)d_in[6];
  const float* lin1_w = (const float*)d_in[7];
  const float* lin1_b = (const float*)d_in[8];
  const float* gw[4]  = {(const float*)d_in[9],  (const float*)d_in[13], (const float*)d_in[17], (const float*)d_in[21]};
  const float* gas[4] = {(const float*)d_in[10], (const float*)d_in[14], (const float*)d_in[18], (const float*)d_in[22]};
  const float* gad[4] = {(const float*)d_in[11], (const float*)d_in[15], (const float*)d_in[19], (const float*)d_in[23]};
  const float* gb[4]  = {(const float*)d_in[12], (const float*)d_in[16], (const float*)d_in[20], (const float*)d_in[24]};
  float* out = (float*)d_out;

  __half* hproj_h = (__half*)d_ws;                          // N*128 fp16
  float*  fws     = (float*)(hproj_h + (size_t)NNODES * 128);
  float* hsmall = fws;                                      // N*32
  float* scs    = hsmall + (size_t)NNODES * 32;             // N*4
  float* scd    = scs    + (size_t)NNODES * 4;              // N*4
  float* pooled = scd    + (size_t)NNODES * 4;              // 64*32
  float* cnt    = pooled + NGRAPH * HIDC;                   // 64
  float* T1     = cnt + NGRAPH;                             // 128*256
  float* Wc     = T1 + 128 * 256;                           // 128*128
  float* b2c    = Wc + 128 * 128;                           // 256
  float* bc     = b2c + 256;                                // 128
  float* soff1  = bc + 128;                                 // 8
  float* Ws1    = soff1 + 8;                                // 128*8
  float* Ws2    = Ws1 + 128 * 8;                            // 32*8
  float* Ws3    = Ws2 + 32 * 8;
  float* Ws4    = Ws3 + 32 * 8;
  int* deg       = (int*)(Ws4 + 32 * 8);                    // N
  int* row_start = deg + NNODES;                            // N+1
  int* col_src   = row_start + NNODES + 1;                  // ETOT
  int* bsum      = col_src + ETOT;                          // 196
  int* boff      = bsum + SCAN_BLOCKS;                      // 196

  // --- weight composition ---
  gemm_f32<<<dim3(2, 4), 256, 0, stream>>>(enc1_w, enc2_w, nullptr, T1, 128, 128, 256);
  gemm_f32<<<dim3(2, 2), 256, 0, stream>>>(T1, gw[0], nullptr, Wc, 128, 256, 128);
  vecmat_fast<<<64, 256, 0, stream>>>(enc1_b, enc2_w, enc2_b, b2c, 128, 256);
  vecmat_fast<<<32, 256, 0, stream>>>(b2c, gw[0], nullptr, bc, 256, 128);
  score_fold_kernel<<<4, 256, 0, stream>>>(Wc, gas[0], gad[0], Ws1, 128);
  score_fold_kernel<<<1, 256, 0, stream>>>(bc, gas[0], gad[0], soff1, 1);
  score_fold_kernel<<<1, 256, 0, stream>>>(gw[1], gas[1], gad[1], Ws2, 32);
  score_fold_kernel<<<1, 256, 0, stream>>>(gw[2], gas[2], gad[2], Ws3, 32);
  score_fold_kernel<<<1, 256, 0, stream>>>(gw[3], gas[3], gad[3], Ws4, 32);

  // --- CSR build (parallel scan) ---
  hipMemsetAsync(deg, 0, NNODES * sizeof(int), stream);
  hist_kernel<<<(ETOT + 255) / 256, 256, 0, stream>>>(ei, deg);
  scan_block_kernel<<<SCAN_BLOCKS, 256, 0, stream>>>(deg, row_start, bsum);
  scan_sums_kernel<<<1, 256, 0, stream>>>(bsum, boff);
  scan_add_kernel<<<SCAN_BLOCKS, 256, 0, stream>>>(boff, row_start);
  hipMemsetAsync(deg, 0, NNODES * sizeof(int), stream);
  scatter_kernel<<<(ETOT + 255) / 256, 256, 0, stream>>>(ei, row_start, deg, col_src);

  dim3 gproj((NNODES + 63) / 64, 2);
  int nodeblocks = (NNODES + 3) / 4;
  int edgeblocks = (NNODES + 7) / 8;

  // --- layer 1 (composite: enc1+enc2+g1 projection in one GEMM) ---
  gemm_h16<<<gproj, 256, 0, stream>>>(x, Wc, bc, hproj_h, NNODES, 128);
  scores_direct<<<nodeblocks, 256, 0, stream>>>(x, Ws1, soff1, scs, scd, 128);
  gat_edge_kernel<<<edgeblocks, 256, 0, stream>>>((const __half2*)hproj_h, scs, scd, row_start, col_src, gb[0], hsmall);

  // --- layers 2..4 ---
  const float* WsL[4] = {Ws1, Ws2, Ws3, Ws4};
  for (int L = 1; L < 4; ++L) {
    gemm_h16<<<gproj, 256, 0, stream>>>(hsmall, gw[L], nullptr, hproj_h, NNODES, 32);
    scores_direct<<<nodeblocks, 256, 0, stream>>>(hsmall, WsL[L], nullptr, scs, scd, 32);
    gat_edge_kernel<<<edgeblocks, 256, 0, stream>>>((const __half2*)hproj_h, scs, scd, row_start, col_src, gb[L], hsmall);
  }

  // --- pooling + classifier ---
  hipMemsetAsync(pooled, 0, (NGRAPH * HIDC + NGRAPH) * sizeof(float), stream);
  pool_kernel<<<POOL_BLOCKS, 256, 0, stream>>>(hsmall, batch, pooled, cnt);
  final_kernel<<<1, 640, 0, stream>>>(pooled, cnt, lin1_w, lin1_b, out);
}

// Round 9
// 504.991 us; speedup vs baseline: 1.6279x; 1.1694x over previous
//
#include <hip/hip_runtime.h>
#include <hip/hip_fp16.h>
#include <math.h>

#define NNODES 50000
#define NEDGES 800000
#define ETOT   (NEDGES + NNODES)
#define HIDC   32
#define NGRAPH 64
#define NCLS   10
#define SLOPE  0.2f
#define SCAN_BLOCKS ((NNODES + 255) / 256)   // 196

__device__ __forceinline__ float lrelu(float v) { return v > 0.f ? v : SLOPE * v; }

// ---------------- CSR build (by dst), includes self loops ----------------
__global__ void hist_kernel(const int* __restrict__ ei, int* __restrict__ deg) {
  int e = blockIdx.x * 256 + threadIdx.x;
  if (e >= ETOT) return;
  int d = (e < NEDGES) ? ei[NEDGES + e] : (e - NEDGES);
  atomicAdd(&deg[d], 1);
}

__global__ __launch_bounds__(256)
void scan_block_kernel(const int* __restrict__ deg, int* __restrict__ row_start,
                       int* __restrict__ bsum) {
  __shared__ int wsum[4];
  int i = blockIdx.x * 256 + threadIdx.x;
  int v = (i < NNODES) ? deg[i] : 0;
  int lane = threadIdx.x & 63, w = threadIdx.x >> 6;
  int x = v;
  #pragma unroll
  for (int d = 1; d < 64; d <<= 1) {
    int y = __shfl_up(x, d);
    if (lane >= d) x += y;
  }
  if (lane == 63) wsum[w] = x;
  __syncthreads();
  int woff = 0;
  #pragma unroll
  for (int j = 0; j < 4; ++j) if (j < w) woff += wsum[j];
  int incl = x + woff;
  if (i < NNODES) row_start[i] = incl - v;
  if (threadIdx.x == 255) bsum[blockIdx.x] = incl;
}

__global__ __launch_bounds__(256)
void scan_sums_kernel(const int* __restrict__ bsum, int* __restrict__ boff) {
  __shared__ int wsum[4];
  int tid = threadIdx.x;
  int v = (tid < SCAN_BLOCKS) ? bsum[tid] : 0;
  int lane = tid & 63, w = tid >> 6;
  int x = v;
  #pragma unroll
  for (int d = 1; d < 64; d <<= 1) {
    int y = __shfl_up(x, d);
    if (lane >= d) x += y;
  }
  if (lane == 63) wsum[w] = x;
  __syncthreads();
  int woff = 0;
  #pragma unroll
  for (int j = 0; j < 4; ++j) if (j < w) woff += wsum[j];
  if (tid < SCAN_BLOCKS) boff[tid] = (x + woff) - v;
}

__global__ __launch_bounds__(256)
void scan_add_kernel(const int* __restrict__ boff, int* __restrict__ row_start) {
  int i = blockIdx.x * 256 + threadIdx.x;
  if (i < NNODES) row_start[i] += boff[blockIdx.x];
  if (i == 0) row_start[NNODES] = ETOT;
}

__global__ void scatter_kernel(const int* __restrict__ ei, const int* __restrict__ row_start,
                               int* __restrict__ cursor, int* __restrict__ col_src) {
  int e = blockIdx.x * 256 + threadIdx.x;
  if (e >= ETOT) return;
  int s, d;
  if (e < NEDGES) { s = ei[e]; d = ei[NEDGES + e]; }
  else { s = d = e - NEDGES; }
  int pos = atomicAdd(&cursor[d], 1);
  col_src[row_start[d] + pos] = s;
}

// ---------------- fp32 tiled GEMM (fp32 out) ----------------
__global__ __launch_bounds__(256)
void gemm_f32(const float* __restrict__ A, const float* __restrict__ B,
              const float* __restrict__ bias, float* __restrict__ C,
              int M, int K, int N) {
  __shared__ float As[32][68];
  __shared__ float Bs[32][68];
  int row0 = blockIdx.x * 64, col0 = blockIdx.y * 64;
  int tid = threadIdx.x;
  int tx = tid & 15, ty = tid >> 4;
  float acc[4][4] = {};
  for (int k0 = 0; k0 < K; k0 += 32) {
    #pragma unroll
    for (int i = 0; i < 8; ++i) {
      int idx = tid + i * 256;
      int r = idx >> 5, c = idx & 31;
      int gr = row0 + r;
      As[c][r] = (gr < M) ? A[(size_t)gr * K + k0 + c] : 0.f;
    }
    #pragma unroll
    for (int i = 0; i < 8; ++i) {
      int idx = tid + i * 256;
      int r = idx >> 6, c = idx & 63;
      Bs[r][c] = B[(size_t)(k0 + r) * N + col0 + c];
    }
    __syncthreads();
    #pragma unroll
    for (int k = 0; k < 32; ++k) {
      float a4[4], b4[4];
      #pragma unroll
      for (int i = 0; i < 4; ++i) a4[i] = As[k][ty * 4 + i];
      #pragma unroll
      for (int j = 0; j < 4; ++j) b4[j] = Bs[k][tx * 4 + j];
      #pragma unroll
      for (int i = 0; i < 4; ++i)
        #pragma unroll
        for (int j = 0; j < 4; ++j)
          acc[i][j] = fmaf(a4[i], b4[j], acc[i][j]);
    }
    __syncthreads();
  }
  #pragma unroll
  for (int i = 0; i < 4; ++i) {
    int gr = row0 + ty * 4 + i;
    if (gr >= M) continue;
    #pragma unroll
    for (int j = 0; j < 4; ++j) {
      int gc = col0 + tx * 4 + j;
      C[(size_t)gr * N + gc] = acc[i][j] + (bias ? bias[gc] : 0.f);
    }
  }
}

// ---------------- wave-per-output vecmat ----------------
__global__ __launch_bounds__(256)
void vecmat_fast(const float* __restrict__ v, const float* __restrict__ W,
                 const float* __restrict__ bias, float* __restrict__ out,
                 int K, int N) {
  int wave = threadIdx.x >> 6, lane = threadIdx.x & 63;
  int j = blockIdx.x * 4 + wave;
  if (j >= N) return;
  float acc = 0.f;
  for (int k = lane; k < K; k += 64)
    acc = fmaf(v[k], W[(size_t)k * N + j], acc);
  #pragma unroll
  for (int d = 32; d >= 1; d >>= 1) acc += __shfl_xor(acc, d);
  if (lane == 0) out[j] = acc + (bias ? bias[j] : 0.f);
}

// Ws[r][j] = sum_c W[r, h*32+c] * a[h][c]
__global__ void score_fold_kernel(const float* __restrict__ W, const float* __restrict__ as_,
                                  const float* __restrict__ ad_, float* __restrict__ Ws, int din) {
  int t = blockIdx.x * 256 + threadIdx.x;
  if (t >= din * 8) return;
  int r = t >> 3, j = t & 7, h = j & 3;
  const float* a = (j < 4) ? as_ : ad_;
  float s = 0.f;
  for (int c = 0; c < 32; ++c) s = fmaf(W[r * 128 + h * 32 + c], a[h * 32 + c], s);
  Ws[t] = s;
}

// ---------------- fp32 tiled GEMM -> fp16 output [M,128] (layer 1 only) ----------------
__global__ __launch_bounds__(256)
void gemm_h16(const float* __restrict__ A, const float* __restrict__ B,
              const float* __restrict__ bias, __half* __restrict__ Ch,
              int M, int K) {
  __shared__ float As[32][68];
  __shared__ float Bs[32][68];
  int row0 = blockIdx.x * 64, col0 = blockIdx.y * 64;
  int tid = threadIdx.x;
  int tx = tid & 15, ty = tid >> 4;
  float acc[4][4] = {};
  for (int k0 = 0; k0 < K; k0 += 32) {
    #pragma unroll
    for (int i = 0; i < 8; ++i) {
      int idx = tid + i * 256;
      int r = idx >> 5, c = idx & 31;
      int gr = row0 + r;
      As[c][r] = (gr < M && (k0 + c) < K) ? A[(size_t)gr * K + k0 + c] : 0.f;
    }
    #pragma unroll
    for (int i = 0; i < 8; ++i) {
      int idx = tid + i * 256;
      int r = idx >> 6, c = idx & 63;
      Bs[r][c] = ((k0 + r) < K) ? B[(size_t)(k0 + r) * 128 + col0 + c] : 0.f;
    }
    __syncthreads();
    #pragma unroll
    for (int k = 0; k < 32; ++k) {
      float a4[4], b4[4];
      #pragma unroll
      for (int i = 0; i < 4; ++i) a4[i] = As[k][ty * 4 + i];
      #pragma unroll
      for (int j = 0; j < 4; ++j) b4[j] = Bs[k][tx * 4 + j];
      #pragma unroll
      for (int i = 0; i < 4; ++i)
        #pragma unroll
        for (int j = 0; j < 4; ++j)
          acc[i][j] = fmaf(a4[i], b4[j], acc[i][j]);
    }
    __syncthreads();
  }
  #pragma unroll
  for (int i = 0; i < 4; ++i) {
    int gr = row0 + ty * 4 + i;
    if (gr >= M) continue;
    int gc0 = col0 + tx * 4;
    float v0 = acc[i][0] + (bias ? bias[gc0]     : 0.f);
    float v1 = acc[i][1] + (bias ? bias[gc0 + 1] : 0.f);
    float v2 = acc[i][2] + (bias ? bias[gc0 + 2] : 0.f);
    float v3 = acc[i][3] + (bias ? bias[gc0 + 3] : 0.f);
    __half2* hp = (__half2*)(Ch + (size_t)gr * 128 + gc0);
    hp[0] = __floats2half2_rn(v0, v1);
    hp[1] = __floats2half2_rn(v2, v3);
  }
}

// ---------------- direct per-node scores (layer 1 only, K=128) ----------------
__global__ __launch_bounds__(256)
void scores_direct(const float* __restrict__ A, const float* __restrict__ Wsg,
                   const float* __restrict__ soff,
                   float* __restrict__ scs, float* __restrict__ scd, int K) {
  __shared__ float ws[8][132];
  int tid = threadIdx.x;
  for (int idx = tid; idx < K * 8; idx += 256)
    ws[idx & 7][idx >> 3] = Wsg[idx];
  __syncthreads();
  int wave = tid >> 6, lane = tid & 63;
  int node = blockIdx.x * 4 + wave;
  if (node >= NNODES) return;
  float x1 = (lane < K) ? A[(size_t)node * K + lane] : 0.f;
  float x2 = (lane + 64 < K) ? A[(size_t)node * K + lane + 64] : 0.f;
  float acc[8];
  #pragma unroll
  for (int j = 0; j < 8; ++j) {
    float a = (lane < K) ? x1 * ws[j][lane] : 0.f;
    if (lane + 64 < K) a = fmaf(x2, ws[j][lane + 64], a);
    acc[j] = a;
  }
  #pragma unroll
  for (int d = 32; d >= 1; d >>= 1)
    #pragma unroll
    for (int j = 0; j < 8; ++j) acc[j] += __shfl_xor(acc[j], d);
  if (lane == 0) {
    float o0 = soff ? soff[0] : 0.f, o1 = soff ? soff[1] : 0.f;
    float o2 = soff ? soff[2] : 0.f, o3 = soff ? soff[3] : 0.f;
    float o4 = soff ? soff[4] : 0.f, o5 = soff ? soff[5] : 0.f;
    float o6 = soff ? soff[6] : 0.f, o7 = soff ? soff[7] : 0.f;
    *(float4*)(scs + (size_t)node * 4) = make_float4(acc[0] + o0, acc[1] + o1, acc[2] + o2, acc[3] + o3);
    *(float4*)(scd + (size_t)node * 4) = make_float4(acc[4] + o4, acc[5] + o5, acc[6] + o6, acc[7] + o7);
  }
}

// ---------------- fused projection+scores for K=32 layers (2..4) ----------------
// W columns live in registers (96 VGPR); node rows staged in LDS; fully
// unrolled 32-step dot per node: 32 broadcast ds_reads + 96 FMA, no barriers
// in the loop. Replaces gemm_h16(K=32) + scores_direct.
#define PS_NODES 64
__global__ __launch_bounds__(256)
void proj_scores_kernel(const float* __restrict__ hin,   // [N,32] fp32
                        const float* __restrict__ W,     // [32,128]
                        const float* __restrict__ Ws,    // [32,8]
                        __half* __restrict__ hproj_h,    // [N,128] fp16 out
                        float* __restrict__ scs, float* __restrict__ scd) {
  __shared__ float hsh[PS_NODES][32];   // 8 KB
  int tid = threadIdx.x;
  int n0 = blockIdx.x * PS_NODES;
  {
    const float4* src = (const float4*)(hin + (size_t)n0 * 32);
    float4* dst = (float4*)&hsh[0][0];
    const int nf4 = PS_NODES * 32 / 4;           // 512
    const int lim = NNODES * 8;                  // total float4 in hin
    for (int i = tid; i < nf4; i += 256) {
      dst[i] = (n0 * 8 + i < lim) ? src[i] : make_float4(0.f, 0.f, 0.f, 0.f);
    }
  }
  int wave = tid >> 6, lane = tid & 63;
  float w0[32], w1[32], wsv[32];
  #pragma unroll
  for (int k = 0; k < 32; ++k) {
    w0[k]  = W[k * 128 + lane];
    w1[k]  = W[k * 128 + 64 + lane];
    wsv[k] = (lane < 8) ? Ws[k * 8 + lane] : 0.f;
  }
  __syncthreads();
  #pragma unroll 1
  for (int ni = 0; ni < 16; ++ni) {
    int nl = wave * 16 + ni;
    int node = n0 + nl;
    if (node >= NNODES) break;      // wave-uniform
    float a0 = 0.f, a1 = 0.f, sa = 0.f;
    #pragma unroll
    for (int k = 0; k < 32; ++k) {
      float hk = hsh[nl][k];
      a0 = fmaf(hk, w0[k], a0);
      a1 = fmaf(hk, w1[k], a1);
      sa = fmaf(hk, wsv[k], sa);
    }
    hproj_h[(size_t)node * 128 + lane]      = __float2half_rn(a0);
    hproj_h[(size_t)node * 128 + 64 + lane] = __float2half_rn(a1);
    if (lane < 4)      scs[(size_t)node * 4 + lane]     = sa;
    else if (lane < 8) scd[(size_t)node * 4 + lane - 4] = sa;
  }
}

// ---------------- fused GAT edge kernel: 2 nodes per wave ----------------
__global__ __launch_bounds__(256)
void gat_edge_kernel(const __half2* __restrict__ hproj_h,
                     const float* __restrict__ scs, const float* __restrict__ scd,
                     const int* __restrict__ row_start, const int* __restrict__ col_src,
                     const float* __restrict__ bias, float* __restrict__ hout) {
  __shared__ int src_sh[4][64];
  __shared__ __align__(16) float al_sh[4][256];
  int wave = threadIdx.x >> 6, lane = threadIdx.x & 63;
  int half = lane >> 5, l32 = lane & 31;
  int nodeBase = blockIdx.x * 8 + wave * 2;
  if (nodeBase >= NNODES) return;
  const uint4* hp4 = (const uint4*)hproj_h;

  int node = nodeBase + half;
  bool nvalid = node < NNODES;
  int s = 0, e = 0;
  if (nvalid) { s = row_start[node]; e = row_start[node + 1]; }
  int deg = e - s;
  int dmax = max(deg, __shfl_xor(deg, 32));

  if (dmax <= 32) {
    float4 sd = make_float4(0.f, 0.f, 0.f, 0.f);
    if (nvalid) sd = *(const float4*)(scd + (size_t)node * 4);
    bool valid = nvalid && (l32 < deg);
    int srcv = 0;
    float4 ss = make_float4(0.f, 0.f, 0.f, 0.f);
    if (valid) {
      srcv = col_src[s + l32];
      ss = *(const float4*)(scs + (size_t)srcv * 4);
    }
    float e0 = lrelu(ss.x + sd.x), e1 = lrelu(ss.y + sd.y);
    float e2 = lrelu(ss.z + sd.z), e3 = lrelu(ss.w + sd.w);
    float m0 = valid ? e0 : -INFINITY, m1 = valid ? e1 : -INFINITY;
    float m2 = valid ? e2 : -INFINITY, m3 = valid ? e3 : -INFINITY;
    #pragma unroll
    for (int d = 16; d >= 1; d >>= 1) {
      m0 = fmaxf(m0, __shfl_xor(m0, d));
      m1 = fmaxf(m1, __shfl_xor(m1, d));
      m2 = fmaxf(m2, __shfl_xor(m2, d));
      m3 = fmaxf(m3, __shfl_xor(m3, d));
    }
    float a0 = valid ? __expf(e0 - m0) : 0.f;
    float a1 = valid ? __expf(e1 - m1) : 0.f;
    float a2 = valid ? __expf(e2 - m2) : 0.f;
    float a3 = valid ? __expf(e3 - m3) : 0.f;
    float d0 = a0, d1 = a1, d2 = a2, d3 = a3;
    #pragma unroll
    for (int d = 16; d >= 1; d >>= 1) {
      d0 += __shfl_xor(d0, d);
      d1 += __shfl_xor(d1, d);
      d2 += __shfl_xor(d2, d);
      d3 += __shfl_xor(d3, d);
    }
    src_sh[wave][lane] = srcv;
    *(float4*)&al_sh[wave][lane * 4] = make_float4(a0, a1, a2, a3);

    int g2 = l32 >> 4;
    int r  = l32 & 15;
    int head = r >> 2;
    float acc[8] = {};
    int ng = (dmax + 1) >> 1;
    for (int jg = 0; jg < ng; ++jg) {
      int j = jg * 2 + g2;
      int slot = half * 32 + j;
      int src = src_sh[wave][slot];
      float al = al_sh[wave][slot * 4 + head];
      uint4 p = hp4[(size_t)src * 16 + r];
      float2 f0 = __half22float2(*(__half2*)&p.x);
      float2 f1 = __half22float2(*(__half2*)&p.y);
      float2 f2 = __half22float2(*(__half2*)&p.z);
      float2 f3 = __half22float2(*(__half2*)&p.w);
      acc[0] = fmaf(al, f0.x, acc[0]); acc[1] = fmaf(al, f0.y, acc[1]);
      acc[2] = fmaf(al, f1.x, acc[2]); acc[3] = fmaf(al, f1.y, acc[3]);
      acc[4] = fmaf(al, f2.x, acc[4]); acc[5] = fmaf(al, f2.y, acc[5]);
      acc[6] = fmaf(al, f3.x, acc[6]); acc[7] = fmaf(al, f3.y, acc[7]);
    }
    float den = (head == 0) ? d0 : (head == 1) ? d1 : (head == 2) ? d2 : d3;
    float rd = 1.f / fmaxf(den, 1e-16f);
    #pragma unroll
    for (int k = 0; k < 8; ++k) acc[k] *= rd;
    #pragma unroll
    for (int k = 0; k < 8; ++k) acc[k] += __shfl_xor(acc[k], 16);
    #pragma unroll
    for (int k = 0; k < 8; ++k) acc[k] += __shfl_xor(acc[k], 4);
    #pragma unroll
    for (int k = 0; k < 8; ++k) acc[k] += __shfl_xor(acc[k], 8);
    if (nvalid && l32 < 4) {
      float o[8];
      #pragma unroll
      for (int k = 0; k < 8; ++k) {
        float v = acc[k] * 0.25f + bias[8 * l32 + k];
        o[k] = v > 0.f ? v : expm1f(v);
      }
      float* op = hout + (size_t)node * 32 + 8 * l32;
      *(float4*)op       = make_float4(o[0], o[1], o[2], o[3]);
      *(float4*)(op + 4) = make_float4(o[4], o[5], o[6], o[7]);
    }
  } else {
    for (int nn = 0; nn < 2; ++nn) {
      int nd = nodeBase + nn;
      if (nd >= NNODES) break;
      int s2 = row_start[nd], e2 = row_start[nd + 1];
      float4 sd = *(const float4*)(scd + (size_t)nd * 4);
      float m0 = -INFINITY, m1 = -INFINITY, m2 = -INFINITY, m3 = -INFINITY;
      for (int i = s2 + lane; i < e2; i += 64) {
        int src = col_src[i];
        float4 ss = *(const float4*)(scs + (size_t)src * 4);
        m0 = fmaxf(m0, lrelu(ss.x + sd.x));
        m1 = fmaxf(m1, lrelu(ss.y + sd.y));
        m2 = fmaxf(m2, lrelu(ss.z + sd.z));
        m3 = fmaxf(m3, lrelu(ss.w + sd.w));
      }
      #pragma unroll
      for (int d = 32; d >= 1; d >>= 1) {
        m0 = fmaxf(m0, __shfl_xor(m0, d));
        m1 = fmaxf(m1, __shfl_xor(m1, d));
        m2 = fmaxf(m2, __shfl_xor(m2, d));
        m3 = fmaxf(m3, __shfl_xor(m3, d));
      }
      int g = lane >> 4, r = lane & 15, head = r >> 2;
      float den0 = 0, den1 = 0, den2 = 0, den3 = 0;
      float acc[8] = {};
      for (int base = s2; base < e2; base += 64) {
        int i = base + lane;
        bool valid = i < e2;
        int srcv = 0;
        float a0 = 0, a1 = 0, a2 = 0, a3 = 0;
        if (valid) {
          srcv = col_src[i];
          float4 ss = *(const float4*)(scs + (size_t)srcv * 4);
          a0 = __expf(lrelu(ss.x + sd.x) - m0);
          a1 = __expf(lrelu(ss.y + sd.y) - m1);
          a2 = __expf(lrelu(ss.z + sd.z) - m2);
          a3 = __expf(lrelu(ss.w + sd.w) - m3);
          den0 += a0; den1 += a1; den2 += a2; den3 += a3;
        }
        src_sh[wave][lane] = srcv;
        *(float4*)&al_sh[wave][lane * 4] = make_float4(a0, a1, a2, a3);
        int cnt = min(64, e2 - base);
        int ngc = (cnt + 3) >> 2;
        for (int jg = 0; jg < ngc; ++jg) {
          int j = jg * 4 + g;
          int src = src_sh[wave][j];
          float al = al_sh[wave][j * 4 + head];
          uint4 p = hp4[(size_t)src * 16 + r];
          float2 f0 = __half22float2(*(__half2*)&p.x);
          float2 f1 = __half22float2(*(__half2*)&p.y);
          float2 f2 = __half22float2(*(__half2*)&p.z);
          float2 f3 = __half22float2(*(__half2*)&p.w);
          acc[0] = fmaf(al, f0.x, acc[0]); acc[1] = fmaf(al, f0.y, acc[1]);
          acc[2] = fmaf(al, f1.x, acc[2]); acc[3] = fmaf(al, f1.y, acc[3]);
          acc[4] = fmaf(al, f2.x, acc[4]); acc[5] = fmaf(al, f2.y, acc[5]);
          acc[6] = fmaf(al, f3.x, acc[6]); acc[7] = fmaf(al, f3.y, acc[7]);
        }
      }
      #pragma unroll
      for (int d = 32; d >= 1; d >>= 1) {
        den0 += __shfl_xor(den0, d);
        den1 += __shfl_xor(den1, d);
        den2 += __shfl_xor(den2, d);
        den3 += __shfl_xor(den3, d);
      }
      float den = (head == 0) ? den0 : (head == 1) ? den1 : (head == 2) ? den2 : den3;
      float rd = 1.f / fmaxf(den, 1e-16f);
      #pragma unroll
      for (int k = 0; k < 8; ++k) acc[k] *= rd;
      #pragma unroll
      for (int d = 4; d <= 32; d <<= 1) {
        #pragma unroll
        for (int k = 0; k < 8; ++k) acc[k] += __shfl_xor(acc[k], d);
      }
      if (lane < 4) {
        float o[8];
        #pragma unroll
        for (int k = 0; k < 8; ++k) {
          float v = acc[k] * 0.25f + bias[8 * lane + k];
          o[k] = v > 0.f ? v : expm1f(v);
        }
        float* op = hout + (size_t)nd * 32 + 8 * lane;
        *(float4*)op       = make_float4(o[0], o[1], o[2], o[3]);
        *(float4*)(op + 4) = make_float4(o[4], o[5], o[6], o[7]);
      }
    }
  }
}

// ---------------- hierarchical global mean pool ----------------
#define POOL_BLOCKS 128
__global__ __launch_bounds__(256)
void pool_kernel(const float* __restrict__ h, const int* __restrict__ batch,
                 float* __restrict__ pooled, float* __restrict__ cnt) {
  __shared__ float acc[NGRAPH][HIDC];
  __shared__ float ccnt[NGRAPH];
  int tid = threadIdx.x;
  const int chunk = (NNODES + POOL_BLOCKS - 1) / POOL_BLOCKS;
  int n0 = blockIdx.x * chunk;
  int n1 = min(n0 + chunk, NNODES);
  if (n0 >= NNODES) return;
  int g0 = batch[n0], g1 = batch[n1 - 1];
  int rows = g1 - g0 + 1;
  for (int idx = tid; idx < rows * HIDC; idx += 256)
    acc[g0 + (idx >> 5)][idx & 31] = 0.f;
  for (int g = tid; g < rows; g += 256) ccnt[g0 + g] = 0.f;
  __syncthreads();
  int c = tid & 31;
  for (int node = n0 + (tid >> 5); node < n1; node += 8) {
    int g = batch[node];
    atomicAdd(&acc[g][c], h[(size_t)node * HIDC + c]);
    if (c == 0) atomicAdd(&ccnt[g], 1.f);
  }
  __syncthreads();
  for (int idx = tid; idx < rows * HIDC; idx += 256) {
    int g = g0 + (idx >> 5), cc = idx & 31;
    atomicAdd(&pooled[g * HIDC + cc], acc[g][cc]);
  }
  for (int g = tid; g < rows; g += 256) atomicAdd(&cnt[g0 + g], ccnt[g0 + g]);
}

__global__ void final_kernel(const float* __restrict__ pooled, const float* __restrict__ cnt,
                             const float* __restrict__ w, const float* __restrict__ b,
                             float* __restrict__ out) {
  int t = threadIdx.x;
  if (t >= NGRAPH * NCLS) return;
  int g = t / NCLS, j = t - g * NCLS;
  float inv = 1.f / fmaxf(cnt[g], 1.f);
  float acc = 0.f;
  #pragma unroll
  for (int c = 0; c < HIDC; ++c)
    acc = fmaf(pooled[g * HIDC + c], w[c * NCLS + j], acc);
  out[t] = acc * inv + b[j];
}

extern "C" void kernel_launch(void* const* d_in, const int* in_sizes, int n_in,
                              void* d_out, int out_size, void* d_ws, size_t ws_size,
                              hipStream_t stream) {
  const float* x      = (const float*)d_in[0];
  const int*   ei     = (const int*)d_in[1];
  const int*   batch  = (const int*)d_in[2];
  const float* enc1_w = (const float*)d_in[3];
  const float* enc1_b = (const float*)d_in[4];
  const float* enc2_w = (const float*)d_in[5];
  const float* enc2_b = (const float*)d_in[6];
  const float* lin1_w = (const float*)d_in[7];
  const float* lin1_b = (const float*)d_in[8];
  const float* gw[4]  = {(const float*)d_in[9],  (const float*)d_in[13], (const float*)d_in[17], (const float*)d_in[21]};
  const float* gas[4] = {(const float*)d_in[10], (const float*)d_in[14], (const float*)d_in[18], (const float*)d_in[22]};
  const float* gad[4] = {(const float*)d_in[11], (const float*)d_in[15], (const float*)d_in[19], (const float*)d_in[23]};
  const float* gb[4]  = {(const float*)d_in[12], (const float*)d_in[16], (const float*)d_in[20], (const float*)d_in[24]};
  float* out = (float*)d_out;

  __half* hproj_h = (__half*)d_ws;                          // N*128 fp16
  float*  fws     = (float*)(hproj_h + (size_t)NNODES * 128);
  float* hsmall = fws;                                      // N*32
  float* scs    = hsmall + (size_t)NNODES * 32;             // N*4
  float* scd    = scs    + (size_t)NNODES * 4;              // N*4
  float* pooled = scd    + (size_t)NNODES * 4;              // 64*32
  float* cnt    = pooled + NGRAPH * HIDC;                   // 64
  float* T1     = cnt + NGRAPH;                             // 128*256
  float* Wc     = T1 + 128 * 256;                           // 128*128
  float* b2c    = Wc + 128 * 128;                           // 256
  float* bc     = b2c + 256;                                // 128
  float* soff1  = bc + 128;                                 // 8
  float* Ws1    = soff1 + 8;                                // 128*8
  float* Ws2    = Ws1 + 128 * 8;                            // 32*8
  float* Ws3    = Ws2 + 32 * 8;
  float* Ws4    = Ws3 + 32 * 8;
  int* deg       = (int*)(Ws4 + 32 * 8);                    // N
  int* row_start = deg + NNODES;                            // N+1
  int* col_src   = row_start + NNODES + 1;                  // ETOT
  int* bsum      = col_src + ETOT;                          // 196
  int* boff      = bsum + SCAN_BLOCKS;                      // 196

  // --- weight composition ---
  gemm_f32<<<dim3(2, 4), 256, 0, stream>>>(enc1_w, enc2_w, nullptr, T1, 128, 128, 256);
  gemm_f32<<<dim3(2, 2), 256, 0, stream>>>(T1, gw[0], nullptr, Wc, 128, 256, 128);
  vecmat_fast<<<64, 256, 0, stream>>>(enc1_b, enc2_w, enc2_b, b2c, 128, 256);
  vecmat_fast<<<32, 256, 0, stream>>>(b2c, gw[0], nullptr, bc, 256, 128);
  score_fold_kernel<<<4, 256, 0, stream>>>(Wc, gas[0], gad[0], Ws1, 128);
  score_fold_kernel<<<1, 256, 0, stream>>>(bc, gas[0], gad[0], soff1, 1);
  score_fold_kernel<<<1, 256, 0, stream>>>(gw[1], gas[1], gad[1], Ws2, 32);
  score_fold_kernel<<<1, 256, 0, stream>>>(gw[2], gas[2], gad[2], Ws3, 32);
  score_fold_kernel<<<1, 256, 0, stream>>>(gw[3], gas[3], gad[3], Ws4, 32);

  // --- CSR build (parallel scan) ---
  hipMemsetAsync(deg, 0, NNODES * sizeof(int), stream);
  hist_kernel<<<(ETOT + 255) / 256, 256, 0, stream>>>(ei, deg);
  scan_block_kernel<<<SCAN_BLOCKS, 256, 0, stream>>>(deg, row_start, bsum);
  scan_sums_kernel<<<1, 256, 0, stream>>>(bsum, boff);
  scan_add_kernel<<<SCAN_BLOCKS, 256, 0, stream>>>(boff, row_start);
  hipMemsetAsync(deg, 0, NNODES * sizeof(int), stream);
  scatter_kernel<<<(ETOT + 255) / 256, 256, 0, stream>>>(ei, row_start, deg, col_src);

  dim3 gproj((NNODES + 63) / 64, 2);
  int nodeblocks = (NNODES + 3) / 4;
  int edgeblocks = (NNODES + 7) / 8;
  int psblocks   = (NNODES + PS_NODES - 1) / PS_NODES;

  // --- layer 1 (composite: enc1+enc2+g1 projection in one GEMM) ---
  gemm_h16<<<gproj, 256, 0, stream>>>(x, Wc, bc, hproj_h, NNODES, 128);
  scores_direct<<<nodeblocks, 256, 0, stream>>>(x, Ws1, soff1, scs, scd, 128);
  gat_edge_kernel<<<edgeblocks, 256, 0, stream>>>((const __half2*)hproj_h, scs, scd, row_start, col_src, gb[0], hsmall);

  // --- layers 2..4: fused register-resident projection + scores ---
  const float* WsL[4] = {Ws1, Ws2, Ws3, Ws4};
  for (int L = 1; L < 4; ++L) {
    proj_scores_kernel<<<psblocks, 256, 0, stream>>>(hsmall, gw[L], WsL[L], hproj_h, scs, scd);
    gat_edge_kernel<<<edgeblocks, 256, 0, stream>>>((const __half2*)hproj_h, scs, scd, row_start, col_src, gb[L], hsmall);
  }

  // --- pooling + classifier ---
  hipMemsetAsync(pooled, 0, (NGRAPH * HIDC + NGRAPH) * sizeof(float), stream);
  pool_kernel<<<POOL_BLOCKS, 256, 0, stream>>>(hsmall, batch, pooled, cnt);
  final_kernel<<<1, 640, 0, stream>>>(pooled, cnt, lin1_w, lin1_b, out);
}

// Round 10
// 456.213 us; speedup vs baseline: 1.8020x; 1.1069x over previous
//
#include <hip/hip_runtime.h>
#include <hip/hip_fp16.h>
#include <math.h>

#define NNODES 50000
#define NEDGES 800000
#define ETOT   (NEDGES + NNODES)
#define HIDC   32
#define NGRAPH 64
#define NCLS   10
#define SLOPE  0.2f
#define SCAN_BLOCKS ((NNODES + 255) / 256)   // 196

typedef _Float16 h8 __attribute__((ext_vector_type(8)));
typedef float f32x4 __attribute__((ext_vector_type(4)));

__device__ __forceinline__ float lrelu(float v) { return v > 0.f ? v : SLOPE * v; }

// ---------------- CSR build (by dst), includes self loops ----------------
__global__ void hist_kernel(const int* __restrict__ ei, int* __restrict__ deg) {
  int e = blockIdx.x * 256 + threadIdx.x;
  if (e >= ETOT) return;
  int d = (e < NEDGES) ? ei[NEDGES + e] : (e - NEDGES);
  atomicAdd(&deg[d], 1);
}

__global__ __launch_bounds__(256)
void scan_block_kernel(const int* __restrict__ deg, int* __restrict__ row_start,
                       int* __restrict__ bsum) {
  __shared__ int wsum[4];
  int i = blockIdx.x * 256 + threadIdx.x;
  int v = (i < NNODES) ? deg[i] : 0;
  int lane = threadIdx.x & 63, w = threadIdx.x >> 6;
  int x = v;
  #pragma unroll
  for (int d = 1; d < 64; d <<= 1) {
    int y = __shfl_up(x, d);
    if (lane >= d) x += y;
  }
  if (lane == 63) wsum[w] = x;
  __syncthreads();
  int woff = 0;
  #pragma unroll
  for (int j = 0; j < 4; ++j) if (j < w) woff += wsum[j];
  int incl = x + woff;
  if (i < NNODES) row_start[i] = incl - v;
  if (threadIdx.x == 255) bsum[blockIdx.x] = incl;
}

__global__ __launch_bounds__(256)
void scan_sums_kernel(const int* __restrict__ bsum, int* __restrict__ boff) {
  __shared__ int wsum[4];
  int tid = threadIdx.x;
  int v = (tid < SCAN_BLOCKS) ? bsum[tid] : 0;
  int lane = tid & 63, w = tid >> 6;
  int x = v;
  #pragma unroll
  for (int d = 1; d < 64; d <<= 1) {
    int y = __shfl_up(x, d);
    if (lane >= d) x += y;
  }
  if (lane == 63) wsum[w] = x;
  __syncthreads();
  int woff = 0;
  #pragma unroll
  for (int j = 0; j < 4; ++j) if (j < w) woff += wsum[j];
  if (tid < SCAN_BLOCKS) boff[tid] = (x + woff) - v;
}

__global__ __launch_bounds__(256)
void scan_add_kernel(const int* __restrict__ boff, int* __restrict__ row_start) {
  int i = blockIdx.x * 256 + threadIdx.x;
  if (i < NNODES) row_start[i] += boff[blockIdx.x];
  if (i == 0) row_start[NNODES] = ETOT;
}

__global__ void scatter_kernel(const int* __restrict__ ei, const int* __restrict__ row_start,
                               int* __restrict__ cursor, int* __restrict__ col_src) {
  int e = blockIdx.x * 256 + threadIdx.x;
  if (e >= ETOT) return;
  int s, d;
  if (e < NEDGES) { s = ei[e]; d = ei[NEDGES + e]; }
  else { s = d = e - NEDGES; }
  int pos = atomicAdd(&cursor[d], 1);
  col_src[row_start[d] + pos] = s;
}

// ---------------- fp32 tiled GEMM (fp32 out) — weight composition ----------------
__global__ __launch_bounds__(256)
void gemm_f32(const float* __restrict__ A, const float* __restrict__ B,
              const float* __restrict__ bias, float* __restrict__ C,
              int M, int K, int N) {
  __shared__ float As[32][68];
  __shared__ float Bs[32][68];
  int row0 = blockIdx.x * 64, col0 = blockIdx.y * 64;
  int tid = threadIdx.x;
  int tx = tid & 15, ty = tid >> 4;
  float acc[4][4] = {};
  for (int k0 = 0; k0 < K; k0 += 32) {
    #pragma unroll
    for (int i = 0; i < 8; ++i) {
      int idx = tid + i * 256;
      int r = idx >> 5, c = idx & 31;
      int gr = row0 + r;
      As[c][r] = (gr < M) ? A[(size_t)gr * K + k0 + c] : 0.f;
    }
    #pragma unroll
    for (int i = 0; i < 8; ++i) {
      int idx = tid + i * 256;
      int r = idx >> 6, c = idx & 63;
      Bs[r][c] = B[(size_t)(k0 + r) * N + col0 + c];
    }
    __syncthreads();
    #pragma unroll
    for (int k = 0; k < 32; ++k) {
      float a4[4], b4[4];
      #pragma unroll
      for (int i = 0; i < 4; ++i) a4[i] = As[k][ty * 4 + i];
      #pragma unroll
      for (int j = 0; j < 4; ++j) b4[j] = Bs[k][tx * 4 + j];
      #pragma unroll
      for (int i = 0; i < 4; ++i)
        #pragma unroll
        for (int j = 0; j < 4; ++j)
          acc[i][j] = fmaf(a4[i], b4[j], acc[i][j]);
    }
    __syncthreads();
  }
  #pragma unroll
  for (int i = 0; i < 4; ++i) {
    int gr = row0 + ty * 4 + i;
    if (gr >= M) continue;
    #pragma unroll
    for (int j = 0; j < 4; ++j) {
      int gc = col0 + tx * 4 + j;
      C[(size_t)gr * N + gc] = acc[i][j] + (bias ? bias[gc] : 0.f);
    }
  }
}

// ---------------- wave-per-output vecmat ----------------
__global__ __launch_bounds__(256)
void vecmat_fast(const float* __restrict__ v, const float* __restrict__ W,
                 const float* __restrict__ bias, float* __restrict__ out,
                 int K, int N) {
  int wave = threadIdx.x >> 6, lane = threadIdx.x & 63;
  int j = blockIdx.x * 4 + wave;
  if (j >= N) return;
  float acc = 0.f;
  for (int k = lane; k < K; k += 64)
    acc = fmaf(v[k], W[(size_t)k * N + j], acc);
  #pragma unroll
  for (int d = 32; d >= 1; d >>= 1) acc += __shfl_xor(acc, d);
  if (lane == 0) out[j] = acc + (bias ? bias[j] : 0.f);
}

// Ws[r][j] = sum_c W[r, h*32+c] * a[h][c]
__global__ void score_fold_kernel(const float* __restrict__ W, const float* __restrict__ as_,
                                  const float* __restrict__ ad_, float* __restrict__ Ws, int din) {
  int t = blockIdx.x * 256 + threadIdx.x;
  if (t >= din * 8) return;
  int r = t >> 3, j = t & 7, h = j & 3;
  const float* a = (j < 4) ? as_ : ad_;
  float s = 0.f;
  for (int c = 0; c < 32; ++c) s = fmaf(W[r * 128 + h * 32 + c], a[h * 32 + c], s);
  Ws[t] = s;
}

// ---------------- build WT[144][128] fp16: cols of Wc, then Ws1, then zero ----------------
__global__ void prep_wT(const float* __restrict__ Wc, const float* __restrict__ Ws1,
                        _Float16* __restrict__ WT) {
  int t = blockIdx.x * 256 + threadIdx.x;
  if (t >= 144 * 128) return;
  int c = t >> 7, k = t & 127;
  float v = 0.f;
  if (c < 128) v = Wc[k * 128 + c];
  else if (c < 136) v = Ws1[k * 8 + (c - 128)];
  WT[t] = (_Float16)v;
}

// ---------------- MFMA layer-1 projection + folded scores ----------------
// C[50048,144] = fp16(x)[.,128] @ fp16 WT^T ; cols 0..127 -> hproj fp16 (+bc),
// cols 128..135 -> scs/scd fp32 (+soff1). 64 rows/block, 4 waves, K-step 32.
__global__ __launch_bounds__(256)
void gemm_mfma(const float* __restrict__ x, const _Float16* __restrict__ WT,
               const float* __restrict__ bc, const float* __restrict__ soff,
               __half* __restrict__ hproj_h,
               float* __restrict__ scs, float* __restrict__ scd) {
  __shared__ _Float16 Ash[64][32];   // 4 KB
  int tid = threadIdx.x, wave = tid >> 6, lane = tid & 63;
  int row0 = blockIdx.x * 64;
  f32x4 acc[9] = {};

  int r = tid >> 2;                    // staging row 0..63
  int kg = (tid & 3) * 8;              // staging k-offset 0,8,16,24
  #pragma unroll 1
  for (int ks = 0; ks < 4; ++ks) {
    // ---- stage A tile (fp32 -> fp16) ----
    float4 v0 = make_float4(0.f, 0.f, 0.f, 0.f), v1 = v0;
    int grow = row0 + r;
    if (grow < NNODES) {
      const float4* xp = (const float4*)(x + (size_t)grow * 128 + ks * 32 + kg);
      v0 = xp[0]; v1 = xp[1];
    }
    __syncthreads();                   // previous iter's reads done
    h8 hv;
    hv[0] = (_Float16)v0.x; hv[1] = (_Float16)v0.y;
    hv[2] = (_Float16)v0.z; hv[3] = (_Float16)v0.w;
    hv[4] = (_Float16)v1.x; hv[5] = (_Float16)v1.y;
    hv[6] = (_Float16)v1.z; hv[7] = (_Float16)v1.w;
    *(h8*)&Ash[r][kg] = hv;
    __syncthreads();
    // ---- A fragment: row = lane&15 (within wave strip), k = (lane>>4)*8.. ----
    h8 af = *(const h8*)&Ash[(wave << 4) + (lane & 15)][(lane >> 4) * 8];
    #pragma unroll
    for (int ct = 0; ct < 9; ++ct) {
      h8 bf = *(const h8*)(WT + (size_t)(ct * 16 + (lane & 15)) * 128 + ks * 32 + (lane >> 4) * 8);
      acc[ct] = __builtin_amdgcn_mfma_f32_16x16x32_f16(af, bf, acc[ct], 0, 0, 0);
    }
  }
  // ---- epilogue: C/D layout col=lane&15, row=(lane>>4)*4+reg ----
  int colL = lane & 15;
  int rbase = row0 + (wave << 4) + ((lane >> 4) << 2);
  #pragma unroll
  for (int reg = 0; reg < 4; ++reg) {
    int node = rbase + reg;
    if (node >= NNODES) continue;
    #pragma unroll
    for (int ct = 0; ct < 8; ++ct) {
      int c = ct * 16 + colL;
      float v = acc[ct][reg] + bc[c];
      hproj_h[(size_t)node * 128 + c] = __float2half_rn(v);
    }
    float sv = acc[8][reg];
    if (colL < 4)      scs[(size_t)node * 4 + colL]     = sv + soff[colL];
    else if (colL < 8) scd[(size_t)node * 4 + colL - 4] = sv + soff[colL];
  }
}

// ---------------- fused projection+scores for K=32 layers (2..4) ----------------
#define PS_NODES 64
__global__ __launch_bounds__(256)
void proj_scores_kernel(const float* __restrict__ hin,
                        const float* __restrict__ W,
                        const float* __restrict__ Ws,
                        __half* __restrict__ hproj_h,
                        float* __restrict__ scs, float* __restrict__ scd) {
  __shared__ float hsh[PS_NODES][32];
  int tid = threadIdx.x;
  int n0 = blockIdx.x * PS_NODES;
  {
    const float4* src = (const float4*)(hin + (size_t)n0 * 32);
    float4* dst = (float4*)&hsh[0][0];
    const int nf4 = PS_NODES * 32 / 4;
    const int lim = NNODES * 8;
    for (int i = tid; i < nf4; i += 256) {
      dst[i] = (n0 * 8 + i < lim) ? src[i] : make_float4(0.f, 0.f, 0.f, 0.f);
    }
  }
  int wave = tid >> 6, lane = tid & 63;
  float w0[32], w1[32], wsv[32];
  #pragma unroll
  for (int k = 0; k < 32; ++k) {
    w0[k]  = W[k * 128 + lane];
    w1[k]  = W[k * 128 + 64 + lane];
    wsv[k] = (lane < 8) ? Ws[k * 8 + lane] : 0.f;
  }
  __syncthreads();
  #pragma unroll 1
  for (int ni = 0; ni < 16; ++ni) {
    int nl = wave * 16 + ni;
    int node = n0 + nl;
    if (node >= NNODES) break;
    float a0 = 0.f, a1 = 0.f, sa = 0.f;
    #pragma unroll
    for (int k = 0; k < 32; ++k) {
      float hk = hsh[nl][k];
      a0 = fmaf(hk, w0[k], a0);
      a1 = fmaf(hk, w1[k], a1);
      sa = fmaf(hk, wsv[k], sa);
    }
    hproj_h[(size_t)node * 128 + lane]      = __float2half_rn(a0);
    hproj_h[(size_t)node * 128 + 64 + lane] = __float2half_rn(a1);
    if (lane < 4)      scs[(size_t)node * 4 + lane]     = sa;
    else if (lane < 8) scd[(size_t)node * 4 + lane - 4] = sa;
  }
}

// ---------------- fused GAT edge kernel: 2 nodes per wave ----------------
__global__ __launch_bounds__(256)
void gat_edge_kernel(const __half2* __restrict__ hproj_h,
                     const float* __restrict__ scs, const float* __restrict__ scd,
                     const int* __restrict__ row_start, const int* __restrict__ col_src,
                     const float* __restrict__ bias, float* __restrict__ hout) {
  __shared__ int src_sh[4][64];
  __shared__ __align__(16) float al_sh[4][256];
  int wave = threadIdx.x >> 6, lane = threadIdx.x & 63;
  int half = lane >> 5, l32 = lane & 31;
  int nodeBase = blockIdx.x * 8 + wave * 2;
  if (nodeBase >= NNODES) return;
  const uint4* hp4 = (const uint4*)hproj_h;

  int node = nodeBase + half;
  bool nvalid = node < NNODES;
  int s = 0, e = 0;
  if (nvalid) { s = row_start[node]; e = row_start[node + 1]; }
  int deg = e - s;
  int dmax = max(deg, __shfl_xor(deg, 32));

  if (dmax <= 32) {
    float4 sd = make_float4(0.f, 0.f, 0.f, 0.f);
    if (nvalid) sd = *(const float4*)(scd + (size_t)node * 4);
    bool valid = nvalid && (l32 < deg);
    int srcv = 0;
    float4 ss = make_float4(0.f, 0.f, 0.f, 0.f);
    if (valid) {
      srcv = col_src[s + l32];
      ss = *(const float4*)(scs + (size_t)srcv * 4);
    }
    float e0 = lrelu(ss.x + sd.x), e1 = lrelu(ss.y + sd.y);
    float e2 = lrelu(ss.z + sd.z), e3 = lrelu(ss.w + sd.w);
    float m0 = valid ? e0 : -INFINITY, m1 = valid ? e1 : -INFINITY;
    float m2 = valid ? e2 : -INFINITY, m3 = valid ? e3 : -INFINITY;
    #pragma unroll
    for (int d = 16; d >= 1; d >>= 1) {
      m0 = fmaxf(m0, __shfl_xor(m0, d));
      m1 = fmaxf(m1, __shfl_xor(m1, d));
      m2 = fmaxf(m2, __shfl_xor(m2, d));
      m3 = fmaxf(m3, __shfl_xor(m3, d));
    }
    float a0 = valid ? __expf(e0 - m0) : 0.f;
    float a1 = valid ? __expf(e1 - m1) : 0.f;
    float a2 = valid ? __expf(e2 - m2) : 0.f;
    float a3 = valid ? __expf(e3 - m3) : 0.f;
    float d0 = a0, d1 = a1, d2 = a2, d3 = a3;
    #pragma unroll
    for (int d = 16; d >= 1; d >>= 1) {
      d0 += __shfl_xor(d0, d);
      d1 += __shfl_xor(d1, d);
      d2 += __shfl_xor(d2, d);
      d3 += __shfl_xor(d3, d);
    }
    src_sh[wave][lane] = srcv;
    *(float4*)&al_sh[wave][lane * 4] = make_float4(a0, a1, a2, a3);

    int g2 = l32 >> 4;
    int r  = l32 & 15;
    int head = r >> 2;
    float acc[8] = {};
    int ng = (dmax + 1) >> 1;
    for (int jg = 0; jg < ng; ++jg) {
      int j = jg * 2 + g2;
      int slot = half * 32 + j;
      int src = src_sh[wave][slot];
      float al = al_sh[wave][slot * 4 + head];
      uint4 p = hp4[(size_t)src * 16 + r];
      float2 f0 = __half22float2(*(__half2*)&p.x);
      float2 f1 = __half22float2(*(__half2*)&p.y);
      float2 f2 = __half22float2(*(__half2*)&p.z);
      float2 f3 = __half22float2(*(__half2*)&p.w);
      acc[0] = fmaf(al, f0.x, acc[0]); acc[1] = fmaf(al, f0.y, acc[1]);
      acc[2] = fmaf(al, f1.x, acc[2]); acc[3] = fmaf(al, f1.y, acc[3]);
      acc[4] = fmaf(al, f2.x, acc[4]); acc[5] = fmaf(al, f2.y, acc[5]);
      acc[6] = fmaf(al, f3.x, acc[6]); acc[7] = fmaf(al, f3.y, acc[7]);
    }
    float den = (head == 0) ? d0 : (head == 1) ? d1 : (head == 2) ? d2 : d3;
    float rd = 1.f / fmaxf(den, 1e-16f);
    #pragma unroll
    for (int k = 0; k < 8; ++k) acc[k] *= rd;
    #pragma unroll
    for (int k = 0; k < 8; ++k) acc[k] += __shfl_xor(acc[k], 16);
    #pragma unroll
    for (int k = 0; k < 8; ++k) acc[k] += __shfl_xor(acc[k], 4);
    #pragma unroll
    for (int k = 0; k < 8; ++k) acc[k] += __shfl_xor(acc[k], 8);
    if (nvalid && l32 < 4) {
      float o[8];
      #pragma unroll
      for (int k = 0; k < 8; ++k) {
        float v = acc[k] * 0.25f + bias[8 * l32 + k];
        o[k] = v > 0.f ? v : expm1f(v);
      }
      float* op = hout + (size_t)node * 32 + 8 * l32;
      *(float4*)op       = make_float4(o[0], o[1], o[2], o[3]);
      *(float4*)(op + 4) = make_float4(o[4], o[5], o[6], o[7]);
    }
  } else {
    for (int nn = 0; nn < 2; ++nn) {
      int nd = nodeBase + nn;
      if (nd >= NNODES) break;
      int s2 = row_start[nd], e2 = row_start[nd + 1];
      float4 sd = *(const float4*)(scd + (size_t)nd * 4);
      float m0 = -INFINITY, m1 = -INFINITY, m2 = -INFINITY, m3 = -INFINITY;
      for (int i = s2 + lane; i < e2; i += 64) {
        int src = col_src[i];
        float4 ss = *(const float4*)(scs + (size_t)src * 4);
        m0 = fmaxf(m0, lrelu(ss.x + sd.x));
        m1 = fmaxf(m1, lrelu(ss.y + sd.y));
        m2 = fmaxf(m2, lrelu(ss.z + sd.z));
        m3 = fmaxf(m3, lrelu(ss.w + sd.w));
      }
      #pragma unroll
      for (int d = 32; d >= 1; d >>= 1) {
        m0 = fmaxf(m0, __shfl_xor(m0, d));
        m1 = fmaxf(m1, __shfl_xor(m1, d));
        m2 = fmaxf(m2, __shfl_xor(m2, d));
        m3 = fmaxf(m3, __shfl_xor(m3, d));
      }
      int g = lane >> 4, r = lane & 15, head = r >> 2;
      float den0 = 0, den1 = 0, den2 = 0, den3 = 0;
      float acc[8] = {};
      for (int base = s2; base < e2; base += 64) {
        int i = base + lane;
        bool valid = i < e2;
        int srcv = 0;
        float a0 = 0, a1 = 0, a2 = 0, a3 = 0;
        if (valid) {
          srcv = col_src[i];
          float4 ss = *(const float4*)(scs + (size_t)srcv * 4);
          a0 = __expf(lrelu(ss.x + sd.x) - m0);
          a1 = __expf(lrelu(ss.y + sd.y) - m1);
          a2 = __expf(lrelu(ss.z + sd.z) - m2);
          a3 = __expf(lrelu(ss.w + sd.w) - m3);
          den0 += a0; den1 += a1; den2 += a2; den3 += a3;
        }
        src_sh[wave][lane] = srcv;
        *(float4*)&al_sh[wave][lane * 4] = make_float4(a0, a1, a2, a3);
        int cnt = min(64, e2 - base);
        int ngc = (cnt + 3) >> 2;
        for (int jg = 0; jg < ngc; ++jg) {
          int j = jg * 4 + g;
          int src = src_sh[wave][j];
          float al = al_sh[wave][j * 4 + head];
          uint4 p = hp4[(size_t)src * 16 + r];
          float2 f0 = __half22float2(*(__half2*)&p.x);
          float2 f1 = __half22float2(*(__half2*)&p.y);
          float2 f2 = __half22float2(*(__half2*)&p.z);
          float2 f3 = __half22float2(*(__half2*)&p.w);
          acc[0] = fmaf(al, f0.x, acc[0]); acc[1] = fmaf(al, f0.y, acc[1]);
          acc[2] = fmaf(al, f1.x, acc[2]); acc[3] = fmaf(al, f1.y, acc[3]);
          acc[4] = fmaf(al, f2.x, acc[4]); acc[5] = fmaf(al, f2.y, acc[5]);
          acc[6] = fmaf(al, f3.x, acc[6]); acc[7] = fmaf(al, f3.y, acc[7]);
        }
      }
      #pragma unroll
      for (int d = 32; d >= 1; d >>= 1) {
        den0 += __shfl_xor(den0, d);
        den1 += __shfl_xor(den1, d);
        den2 += __shfl_xor(den2, d);
        den3 += __shfl_xor(den3, d);
      }
      float den = (head == 0) ? den0 : (head == 1) ? den1 : (head == 2) ? den2 : den3;
      float rd = 1.f / fmaxf(den, 1e-16f);
      #pragma unroll
      for (int k = 0; k < 8; ++k) acc[k] *= rd;
      #pragma unroll
      for (int d = 4; d <= 32; d <<= 1) {
        #pragma unroll
        for (int k = 0; k < 8; ++k) acc[k] += __shfl_xor(acc[k], d);
      }
      if (lane < 4) {
        float o[8];
        #pragma unroll
        for (int k = 0; k < 8; ++k) {
          float v = acc[k] * 0.25f + bias[8 * lane + k];
          o[k] = v > 0.f ? v : expm1f(v);
        }
        float* op = hout + (size_t)nd * 32 + 8 * lane;
        *(float4*)op       = make_float4(o[0], o[1], o[2], o[3]);
        *(float4*)(op + 4) = make_float4(o[4], o[5], o[6], o[7]);
      }
    }
  }
}

// ---------------- hierarchical global mean pool ----------------
#define POOL_BLOCKS 128
__global__ __launch_bounds__(256)
void pool_kernel(const float* __restrict__ h, const int* __restrict__ batch,
                 float* __restrict__ pooled, float* __restrict__ cnt) {
  __shared__ float acc[NGRAPH][HIDC];
  __shared__ float ccnt[NGRAPH];
  int tid = threadIdx.x;
  const int chunk = (NNODES + POOL_BLOCKS - 1) / POOL_BLOCKS;
  int n0 = blockIdx.x * chunk;
  int n1 = min(n0 + chunk, NNODES);
  if (n0 >= NNODES) return;
  int g0 = batch[n0], g1 = batch[n1 - 1];
  int rows = g1 - g0 + 1;
  for (int idx = tid; idx < rows * HIDC; idx += 256)
    acc[g0 + (idx >> 5)][idx & 31] = 0.f;
  for (int g = tid; g < rows; g += 256) ccnt[g0 + g] = 0.f;
  __syncthreads();
  int c = tid & 31;
  for (int node = n0 + (tid >> 5); node < n1; node += 8) {
    int g = batch[node];
    atomicAdd(&acc[g][c], h[(size_t)node * HIDC + c]);
    if (c == 0) atomicAdd(&ccnt[g], 1.f);
  }
  __syncthreads();
  for (int idx = tid; idx < rows * HIDC; idx += 256) {
    int g = g0 + (idx >> 5), cc = idx & 31;
    atomicAdd(&pooled[g * HIDC + cc], acc[g][cc]);
  }
  for (int g = tid; g < rows; g += 256) atomicAdd(&cnt[g0 + g], ccnt[g0 + g]);
}

__global__ void final_kernel(const float* __restrict__ pooled, const float* __restrict__ cnt,
                             const float* __restrict__ w, const float* __restrict__ b,
                             float* __restrict__ out) {
  int t = threadIdx.x;
  if (t >= NGRAPH * NCLS) return;
  int g = t / NCLS, j = t - g * NCLS;
  float inv = 1.f / fmaxf(cnt[g], 1.f);
  float acc = 0.f;
  #pragma unroll
  for (int c = 0; c < HIDC; ++c)
    acc = fmaf(pooled[g * HIDC + c], w[c * NCLS + j], acc);
  out[t] = acc * inv + b[j];
}

extern "C" void kernel_launch(void* const* d_in, const int* in_sizes, int n_in,
                              void* d_out, int out_size, void* d_ws, size_t ws_size,
                              hipStream_t stream) {
  const float* x      = (const float*)d_in[0];
  const int*   ei     = (const int*)d_in[1];
  const int*   batch  = (const int*)d_in[2];
  const float* enc1_w = (const float*)d_in[3];
  const float* enc1_b = (const float*)d_in[4];
  const float* enc2_w = (const float*)d_in[5];
  const float* enc2_b = (const float*)d_in[6];
  const float* lin1_w = (const float*)d_in[7];
  const float* lin1_b = (const float*)d_in[8];
  const float* gw[4]  = {(const float*)d_in[9],  (const float*)d_in[13], (const float*)d_in[17], (const float*)d_in[21]};
  const float* gas[4] = {(const float*)d_in[10], (const float*)d_in[14], (const float*)d_in[18], (const float*)d_in[22]};
  const float* gad[4] = {(const float*)d_in[11], (const float*)d_in[15], (const float*)d_in[19], (const float*)d_in[23]};
  const float* gb[4]  = {(const float*)d_in[12], (const float*)d_in[16], (const float*)d_in[20], (const float*)d_in[24]};
  float* out = (float*)d_out;

  __half* hproj_h   = (__half*)d_ws;                          // N*128 fp16
  _Float16* WT      = (_Float16*)(hproj_h + (size_t)NNODES * 128);  // 144*128 fp16
  float*  fws       = (float*)(WT + 144 * 128);
  float* hsmall = fws;                                        // N*32
  float* scs    = hsmall + (size_t)NNODES * 32;               // N*4
  float* scd    = scs    + (size_t)NNODES * 4;                // N*4
  float* pooled = scd    + (size_t)NNODES * 4;                // 64*32
  float* cnt    = pooled + NGRAPH * HIDC;                     // 64
  float* T1     = cnt + NGRAPH;                               // 128*256
  float* Wc     = T1 + 128 * 256;                             // 128*128
  float* b2c    = Wc + 128 * 128;                             // 256
  float* bc     = b2c + 256;                                  // 128
  float* soff1  = bc + 128;                                   // 8
  float* Ws1    = soff1 + 8;                                  // 128*8
  float* Ws2    = Ws1 + 128 * 8;                              // 32*8
  float* Ws3    = Ws2 + 32 * 8;
  float* Ws4    = Ws3 + 32 * 8;
  int* deg       = (int*)(Ws4 + 32 * 8);                      // N
  int* row_start = deg + NNODES;                              // N+1
  int* col_src   = row_start + NNODES + 1;                    // ETOT
  int* bsum      = col_src + ETOT;                            // 196
  int* boff      = bsum + SCAN_BLOCKS;                        // 196

  // --- weight composition ---
  gemm_f32<<<dim3(2, 4), 256, 0, stream>>>(enc1_w, enc2_w, nullptr, T1, 128, 128, 256);
  gemm_f32<<<dim3(2, 2), 256, 0, stream>>>(T1, gw[0], nullptr, Wc, 128, 256, 128);
  vecmat_fast<<<64, 256, 0, stream>>>(enc1_b, enc2_w, enc2_b, b2c, 128, 256);
  vecmat_fast<<<32, 256, 0, stream>>>(b2c, gw[0], nullptr, bc, 256, 128);
  score_fold_kernel<<<4, 256, 0, stream>>>(Wc, gas[0], gad[0], Ws1, 128);
  score_fold_kernel<<<1, 256, 0, stream>>>(bc, gas[0], gad[0], soff1, 1);
  score_fold_kernel<<<1, 256, 0, stream>>>(gw[1], gas[1], gad[1], Ws2, 32);
  score_fold_kernel<<<1, 256, 0, stream>>>(gw[2], gas[2], gad[2], Ws3, 32);
  score_fold_kernel<<<1, 256, 0, stream>>>(gw[3], gas[3], gad[3], Ws4, 32);
  prep_wT<<<72, 256, 0, stream>>>(Wc, Ws1, WT);

  // --- CSR build (parallel scan) ---
  hipMemsetAsync(deg, 0, NNODES * sizeof(int), stream);
  hist_kernel<<<(ETOT + 255) / 256, 256, 0, stream>>>(ei, deg);
  scan_block_kernel<<<SCAN_BLOCKS, 256, 0, stream>>>(deg, row_start, bsum);
  scan_sums_kernel<<<1, 256, 0, stream>>>(bsum, boff);
  scan_add_kernel<<<SCAN_BLOCKS, 256, 0, stream>>>(boff, row_start);
  hipMemsetAsync(deg, 0, NNODES * sizeof(int), stream);
  scatter_kernel<<<(ETOT + 255) / 256, 256, 0, stream>>>(ei, row_start, deg, col_src);

  int nodeblocks64 = (NNODES + 63) / 64;   // 782
  int edgeblocks = (NNODES + 7) / 8;
  int psblocks   = (NNODES + PS_NODES - 1) / PS_NODES;

  // --- layer 1: MFMA composite projection + folded scores ---
  gemm_mfma<<<nodeblocks64, 256, 0, stream>>>(x, WT, bc, soff1, hproj_h, scs, scd);
  gat_edge_kernel<<<edgeblocks, 256, 0, stream>>>((const __half2*)hproj_h, scs, scd, row_start, col_src, gb[0], hsmall);

  // --- layers 2..4: fused register-resident projection + scores ---
  const float* WsL[4] = {Ws1, Ws2, Ws3, Ws4};
  for (int L = 1; L < 4; ++L) {
    proj_scores_kernel<<<psblocks, 256, 0, stream>>>(hsmall, gw[L], WsL[L], hproj_h, scs, scd);
    gat_edge_kernel<<<edgeblocks, 256, 0, stream>>>((const __half2*)hproj_h, scs, scd, row_start, col_src, gb[L], hsmall);
  }

  // --- pooling + classifier ---
  hipMemsetAsync(pooled, 0, (NGRAPH * HIDC + NGRAPH) * sizeof(float), stream);
  pool_kernel<<<POOL_BLOCKS, 256, 0, stream>>>(hsmall, batch, pooled, cnt);
  final_kernel<<<1, 640, 0, stream>>>(pooled, cnt, lin1_w, lin1_b, out);
}

// Round 11
// 398.350 us; speedup vs baseline: 2.0637x; 1.1453x over previous
//
#include <hip/hip_runtime.h>
#include <hip/hip_fp16.h>
#include <math.h>

#define NNODES 50000
#define NEDGES 800000
#define ETOT   (NEDGES + NNODES)
#define HIDC   32
#define NGRAPH 64
#define NCLS   10
#define SLOPE  0.2f
#define SCAN_BLOCKS ((NNODES + 255) / 256)   // 196

typedef _Float16 h8 __attribute__((ext_vector_type(8)));
typedef float f32x4 __attribute__((ext_vector_type(4)));

__device__ __forceinline__ float lrelu(float v) { return v > 0.f ? v : SLOPE * v; }

// ---------------- CSR build (by dst), includes self loops ----------------
// hist: atomic rank capture -> epos (removes atomics from scatter pass)
__global__ void hist_kernel(const int* __restrict__ ei, int* __restrict__ deg,
                            int* __restrict__ epos) {
  int base = blockIdx.x * 1024 + threadIdx.x;
  #pragma unroll
  for (int u = 0; u < 4; ++u) {
    int e = base + u * 256;
    if (e < ETOT) {
      int d = (e < NEDGES) ? ei[NEDGES + e] : (e - NEDGES);
      epos[e] = atomicAdd(&deg[d], 1);
    }
  }
}

__global__ __launch_bounds__(256)
void scan_block_kernel(const int* __restrict__ deg, int* __restrict__ row_start,
                       int* __restrict__ bsum) {
  __shared__ int wsum[4];
  int i = blockIdx.x * 256 + threadIdx.x;
  int v = (i < NNODES) ? deg[i] : 0;
  int lane = threadIdx.x & 63, w = threadIdx.x >> 6;
  int x = v;
  #pragma unroll
  for (int d = 1; d < 64; d <<= 1) {
    int y = __shfl_up(x, d);
    if (lane >= d) x += y;
  }
  if (lane == 63) wsum[w] = x;
  __syncthreads();
  int woff = 0;
  #pragma unroll
  for (int j = 0; j < 4; ++j) if (j < w) woff += wsum[j];
  int incl = x + woff;
  if (i < NNODES) row_start[i] = incl - v;
  if (threadIdx.x == 255) bsum[blockIdx.x] = incl;
}

__global__ __launch_bounds__(256)
void scan_sums_kernel(const int* __restrict__ bsum, int* __restrict__ boff) {
  __shared__ int wsum[4];
  int tid = threadIdx.x;
  int v = (tid < SCAN_BLOCKS) ? bsum[tid] : 0;
  int lane = tid & 63, w = tid >> 6;
  int x = v;
  #pragma unroll
  for (int d = 1; d < 64; d <<= 1) {
    int y = __shfl_up(x, d);
    if (lane >= d) x += y;
  }
  if (lane == 63) wsum[w] = x;
  __syncthreads();
  int woff = 0;
  #pragma unroll
  for (int j = 0; j < 4; ++j) if (j < w) woff += wsum[j];
  if (tid < SCAN_BLOCKS) boff[tid] = (x + woff) - v;
}

__global__ __launch_bounds__(256)
void scan_add_kernel(const int* __restrict__ boff, int* __restrict__ row_start) {
  int i = blockIdx.x * 256 + threadIdx.x;
  if (i < NNODES) row_start[i] += boff[blockIdx.x];
  if (i == 0) row_start[NNODES] = ETOT;
}

// atomic-free scatter, 4 independent edges per thread
__global__ void scatter_kernel(const int* __restrict__ ei, const int* __restrict__ row_start,
                               const int* __restrict__ epos, int* __restrict__ col_src) {
  int base = blockIdx.x * 1024 + threadIdx.x;
  #pragma unroll
  for (int u = 0; u < 4; ++u) {
    int e = base + u * 256;
    if (e < ETOT) {
      int s, d;
      if (e < NEDGES) { s = ei[e]; d = ei[NEDGES + e]; }
      else { s = d = e - NEDGES; }
      col_src[row_start[d] + epos[e]] = s;
    }
  }
}

// ---------------- weight composition: 3 merged kernels ----------------
__device__ void gemm_tile(const float* __restrict__ A, const float* __restrict__ B,
                          float* __restrict__ C, int K, int N, int row0, int col0,
                          float (*As)[68], float (*Bs)[68]) {
  int tid = threadIdx.x;
  int tx = tid & 15, ty = tid >> 4;
  float acc[4][4] = {};
  for (int k0 = 0; k0 < K; k0 += 32) {
    #pragma unroll
    for (int i = 0; i < 8; ++i) {
      int idx = tid + i * 256;
      int r = idx >> 5, c = idx & 31;
      As[c][r] = A[(size_t)(row0 + r) * K + k0 + c];
    }
    #pragma unroll
    for (int i = 0; i < 8; ++i) {
      int idx = tid + i * 256;
      int r = idx >> 6, c = idx & 63;
      Bs[r][c] = B[(size_t)(k0 + r) * N + col0 + c];
    }
    __syncthreads();
    #pragma unroll
    for (int k = 0; k < 32; ++k) {
      float a4[4], b4[4];
      #pragma unroll
      for (int i = 0; i < 4; ++i) a4[i] = As[k][ty * 4 + i];
      #pragma unroll
      for (int j = 0; j < 4; ++j) b4[j] = Bs[k][tx * 4 + j];
      #pragma unroll
      for (int i = 0; i < 4; ++i)
        #pragma unroll
        for (int j = 0; j < 4; ++j)
          acc[i][j] = fmaf(a4[i], b4[j], acc[i][j]);
    }
    __syncthreads();
  }
  #pragma unroll
  for (int i = 0; i < 4; ++i)
    #pragma unroll
    for (int j = 0; j < 4; ++j)
      C[(size_t)(row0 + ty * 4 + i) * N + col0 + tx * 4 + j] = acc[i][j];
}

// stage 1: T1 = enc1_w@enc2_w (blk 0..7) | b2c + pooled-zero (blk 8) | Ws2/3/4 folds (blk 9..11)
__global__ __launch_bounds__(256)
void wprep1(const float* __restrict__ enc1_w, const float* __restrict__ enc2_w,
            const float* __restrict__ enc1_b, const float* __restrict__ enc2_b,
            const float* __restrict__ gw1, const float* __restrict__ gas1, const float* __restrict__ gad1,
            const float* __restrict__ gw2, const float* __restrict__ gas2, const float* __restrict__ gad2,
            const float* __restrict__ gw3, const float* __restrict__ gas3, const float* __restrict__ gad3,
            float* __restrict__ T1, float* __restrict__ b2c,
            float* __restrict__ Ws2, float* __restrict__ Ws3, float* __restrict__ Ws4,
            float* __restrict__ pooled) {
  __shared__ float As[32][68];
  __shared__ float Bs[32][68];
  int b = blockIdx.x, tid = threadIdx.x;
  if (b < 8) {
    gemm_tile(enc1_w, enc2_w, T1, 128, 256, (b >> 2) * 64, (b & 3) * 64, As, Bs);
  } else if (b == 8) {
    float acc = enc2_b[tid];
    for (int k = 0; k < 128; ++k) acc = fmaf(enc1_b[k], enc2_w[k * 256 + tid], acc);
    b2c[tid] = acc;
    for (int i = tid; i < NGRAPH * HIDC + NGRAPH; i += 256) pooled[i] = 0.f;
  } else {
    const float* W   = (b == 9) ? gw1  : (b == 10) ? gw2  : gw3;
    const float* as_ = (b == 9) ? gas1 : (b == 10) ? gas2 : gas3;
    const float* ad_ = (b == 9) ? gad1 : (b == 10) ? gad2 : gad3;
    float* Ws        = (b == 9) ? Ws2  : (b == 10) ? Ws3  : Ws4;
    int r = tid >> 3, j = tid & 7, h = j & 3;
    const float* a = (j < 4) ? as_ : ad_;
    float s = 0.f;
    for (int c = 0; c < 32; ++c) s = fmaf(W[r * 128 + h * 32 + c], a[h * 32 + c], s);
    Ws[tid] = s;
  }
}

// stage 2: Wc = T1@g1_w (blk 0..3) | bc = b2c@g1_w (blk 4)
__global__ __launch_bounds__(256)
void wprep2(const float* __restrict__ T1, const float* __restrict__ gw0,
            const float* __restrict__ b2c, float* __restrict__ Wc, float* __restrict__ bc) {
  __shared__ float As[32][68];
  __shared__ float Bs[32][68];
  int b = blockIdx.x, tid = threadIdx.x;
  if (b < 4) {
    gemm_tile(T1, gw0, Wc, 256, 128, (b >> 1) * 64, (b & 1) * 64, As, Bs);
  } else if (tid < 128) {
    float acc = 0.f;
    for (int k = 0; k < 256; ++k) acc = fmaf(b2c[k], gw0[k * 128 + tid], acc);
    bc[tid] = acc;
  }
}

// stage 3: WT[144][128] fp16 (copy cols + fold cols + zero pad) | soff1
__global__ __launch_bounds__(256)
void wprep3(const float* __restrict__ Wc, const float* __restrict__ gas0,
            const float* __restrict__ gad0, const float* __restrict__ bc,
            _Float16* __restrict__ WT, float* __restrict__ soff1) {
  int b = blockIdx.x, tid = threadIdx.x;
  if (b < 8) {
    #pragma unroll
    for (int i = 0; i < 8; ++i) {
      int t = b * 2048 + i * 256 + tid;
      int c = t >> 7, k = t & 127;
      WT[t] = (_Float16)Wc[k * 128 + c];
    }
  } else {
    for (int idx = tid; idx < 1024; idx += 256) {
      int j = idx >> 7, k = idx & 127, h = j & 3;
      const float* a = (j < 4) ? gas0 : gad0;
      float s = 0.f;
      for (int c = 0; c < 32; ++c) s = fmaf(Wc[k * 128 + h * 32 + c], a[h * 32 + c], s);
      WT[(size_t)(128 + j) * 128 + k] = (_Float16)s;
    }
    for (int idx = tid; idx < 1024; idx += 256)
      WT[(size_t)136 * 128 + idx] = (_Float16)0.f;
    if (tid < 8) {
      int h = tid & 3;
      const float* a = (tid < 4) ? gas0 : gad0;
      float s = 0.f;
      for (int c = 0; c < 32; ++c) s = fmaf(bc[h * 32 + c], a[h * 32 + c], s);
      soff1[tid] = s;
    }
  }
}

// ---------------- MFMA layer-1 projection + folded scores ----------------
__global__ __launch_bounds__(256)
void gemm_mfma(const float* __restrict__ x, const _Float16* __restrict__ WT,
               const float* __restrict__ bc, const float* __restrict__ soff,
               __half* __restrict__ hproj_h,
               float* __restrict__ scs, float* __restrict__ scd) {
  __shared__ _Float16 Ash[64][32];
  int tid = threadIdx.x, wave = tid >> 6, lane = tid & 63;
  int row0 = blockIdx.x * 64;
  f32x4 acc[9] = {};

  int r = tid >> 2;
  int kg = (tid & 3) * 8;
  #pragma unroll 1
  for (int ks = 0; ks < 4; ++ks) {
    float4 v0 = make_float4(0.f, 0.f, 0.f, 0.f), v1 = v0;
    int grow = row0 + r;
    if (grow < NNODES) {
      const float4* xp = (const float4*)(x + (size_t)grow * 128 + ks * 32 + kg);
      v0 = xp[0]; v1 = xp[1];
    }
    __syncthreads();
    h8 hv;
    hv[0] = (_Float16)v0.x; hv[1] = (_Float16)v0.y;
    hv[2] = (_Float16)v0.z; hv[3] = (_Float16)v0.w;
    hv[4] = (_Float16)v1.x; hv[5] = (_Float16)v1.y;
    hv[6] = (_Float16)v1.z; hv[7] = (_Float16)v1.w;
    *(h8*)&Ash[r][kg] = hv;
    __syncthreads();
    h8 af = *(const h8*)&Ash[(wave << 4) + (lane & 15)][(lane >> 4) * 8];
    #pragma unroll
    for (int ct = 0; ct < 9; ++ct) {
      h8 bf = *(const h8*)(WT + (size_t)(ct * 16 + (lane & 15)) * 128 + ks * 32 + (lane >> 4) * 8);
      acc[ct] = __builtin_amdgcn_mfma_f32_16x16x32_f16(af, bf, acc[ct], 0, 0, 0);
    }
  }
  int colL = lane & 15;
  int rbase = row0 + (wave << 4) + ((lane >> 4) << 2);
  #pragma unroll
  for (int reg = 0; reg < 4; ++reg) {
    int node = rbase + reg;
    if (node >= NNODES) continue;
    #pragma unroll
    for (int ct = 0; ct < 8; ++ct) {
      int c = ct * 16 + colL;
      float v = acc[ct][reg] + bc[c];
      hproj_h[(size_t)node * 128 + c] = __float2half_rn(v);
    }
    float sv = acc[8][reg];
    if (colL < 4)      scs[(size_t)node * 4 + colL]     = sv + soff[colL];
    else if (colL < 8) scd[(size_t)node * 4 + colL - 4] = sv + soff[colL];
  }
}

// ---------------- fused projection+scores for K=32 layers (2..4) ----------------
#define PS_NODES 64
__global__ __launch_bounds__(256)
void proj_scores_kernel(const float* __restrict__ hin,
                        const float* __restrict__ W,
                        const float* __restrict__ Ws,
                        __half* __restrict__ hproj_h,
                        float* __restrict__ scs, float* __restrict__ scd) {
  __shared__ float hsh[PS_NODES][32];
  int tid = threadIdx.x;
  int n0 = blockIdx.x * PS_NODES;
  {
    const float4* src = (const float4*)(hin + (size_t)n0 * 32);
    float4* dst = (float4*)&hsh[0][0];
    const int nf4 = PS_NODES * 32 / 4;
    const int lim = NNODES * 8;
    for (int i = tid; i < nf4; i += 256) {
      dst[i] = (n0 * 8 + i < lim) ? src[i] : make_float4(0.f, 0.f, 0.f, 0.f);
    }
  }
  int wave = tid >> 6, lane = tid & 63;
  float w0[32], w1[32], wsv[32];
  #pragma unroll
  for (int k = 0; k < 32; ++k) {
    w0[k]  = W[k * 128 + lane];
    w1[k]  = W[k * 128 + 64 + lane];
    wsv[k] = (lane < 8) ? Ws[k * 8 + lane] : 0.f;
  }
  __syncthreads();
  #pragma unroll 1
  for (int ni = 0; ni < 16; ++ni) {
    int nl = wave * 16 + ni;
    int node = n0 + nl;
    if (node >= NNODES) break;
    float a0 = 0.f, a1 = 0.f, sa = 0.f;
    #pragma unroll
    for (int k = 0; k < 32; ++k) {
      float hk = hsh[nl][k];
      a0 = fmaf(hk, w0[k], a0);
      a1 = fmaf(hk, w1[k], a1);
      sa = fmaf(hk, wsv[k], sa);
    }
    hproj_h[(size_t)node * 128 + lane]      = __float2half_rn(a0);
    hproj_h[(size_t)node * 128 + 64 + lane] = __float2half_rn(a1);
    if (lane < 4)      scs[(size_t)node * 4 + lane]     = sa;
    else if (lane < 8) scd[(size_t)node * 4 + lane - 4] = sa;
  }
}

// ---------------- fused GAT edge kernel: 2 nodes per wave ----------------
__global__ __launch_bounds__(256)
void gat_edge_kernel(const __half2* __restrict__ hproj_h,
                     const float* __restrict__ scs, const float* __restrict__ scd,
                     const int* __restrict__ row_start, const int* __restrict__ col_src,
                     const float* __restrict__ bias, float* __restrict__ hout) {
  __shared__ int src_sh[4][64];
  __shared__ __align__(16) float al_sh[4][256];
  int wave = threadIdx.x >> 6, lane = threadIdx.x & 63;
  int half = lane >> 5, l32 = lane & 31;
  int nodeBase = blockIdx.x * 8 + wave * 2;
  if (nodeBase >= NNODES) return;
  const uint4* hp4 = (const uint4*)hproj_h;

  int node = nodeBase + half;
  bool nvalid = node < NNODES;
  int s = 0, e = 0;
  if (nvalid) { s = row_start[node]; e = row_start[node + 1]; }
  int deg = e - s;
  int dmax = max(deg, __shfl_xor(deg, 32));

  if (dmax <= 32) {
    float4 sd = make_float4(0.f, 0.f, 0.f, 0.f);
    if (nvalid) sd = *(const float4*)(scd + (size_t)node * 4);
    bool valid = nvalid && (l32 < deg);
    int srcv = 0;
    float4 ss = make_float4(0.f, 0.f, 0.f, 0.f);
    if (valid) {
      srcv = col_src[s + l32];
      ss = *(const float4*)(scs + (size_t)srcv * 4);
    }
    float e0 = lrelu(ss.x + sd.x), e1 = lrelu(ss.y + sd.y);
    float e2 = lrelu(ss.z + sd.z), e3 = lrelu(ss.w + sd.w);
    float m0 = valid ? e0 : -INFINITY, m1 = valid ? e1 : -INFINITY;
    float m2 = valid ? e2 : -INFINITY, m3 = valid ? e3 : -INFINITY;
    #pragma unroll
    for (int d = 16; d >= 1; d >>= 1) {
      m0 = fmaxf(m0, __shfl_xor(m0, d));
      m1 = fmaxf(m1, __shfl_xor(m1, d));
      m2 = fmaxf(m2, __shfl_xor(m2, d));
      m3 = fmaxf(m3, __shfl_xor(m3, d));
    }
    float a0 = valid ? __expf(e0 - m0) : 0.f;
    float a1 = valid ? __expf(e1 - m1) : 0.f;
    float a2 = valid ? __expf(e2 - m2) : 0.f;
    float a3 = valid ? __expf(e3 - m3) : 0.f;
    float d0 = a0, d1 = a1, d2 = a2, d3 = a3;
    #pragma unroll
    for (int d = 16; d >= 1; d >>= 1) {
      d0 += __shfl_xor(d0, d);
      d1 += __shfl_xor(d1, d);
      d2 += __shfl_xor(d2, d);
      d3 += __shfl_xor(d3, d);
    }
    src_sh[wave][lane] = srcv;
    *(float4*)&al_sh[wave][lane * 4] = make_float4(a0, a1, a2, a3);

    int g2 = l32 >> 4;
    int r  = l32 & 15;
    int head = r >> 2;
    float acc[8] = {};
    int ng = (dmax + 1) >> 1;
    for (int jg = 0; jg < ng; ++jg) {
      int j = jg * 2 + g2;
      int slot = half * 32 + j;
      int src = src_sh[wave][slot];
      float al = al_sh[wave][slot * 4 + head];
      uint4 p = hp4[(size_t)src * 16 + r];
      float2 f0 = __half22float2(*(__half2*)&p.x);
      float2 f1 = __half22float2(*(__half2*)&p.y);
      float2 f2 = __half22float2(*(__half2*)&p.z);
      float2 f3 = __half22float2(*(__half2*)&p.w);
      acc[0] = fmaf(al, f0.x, acc[0]); acc[1] = fmaf(al, f0.y, acc[1]);
      acc[2] = fmaf(al, f1.x, acc[2]); acc[3] = fmaf(al, f1.y, acc[3]);
      acc[4] = fmaf(al, f2.x, acc[4]); acc[5] = fmaf(al, f2.y, acc[5]);
      acc[6] = fmaf(al, f3.x, acc[6]); acc[7] = fmaf(al, f3.y, acc[7]);
    }
    float den = (head == 0) ? d0 : (head == 1) ? d1 : (head == 2) ? d2 : d3;
    float rd = 1.f / fmaxf(den, 1e-16f);
    #pragma unroll
    for (int k = 0; k < 8; ++k) acc[k] *= rd;
    #pragma unroll
    for (int k = 0; k < 8; ++k) acc[k] += __shfl_xor(acc[k], 16);
    #pragma unroll
    for (int k = 0; k < 8; ++k) acc[k] += __shfl_xor(acc[k], 4);
    #pragma unroll
    for (int k = 0; k < 8; ++k) acc[k] += __shfl_xor(acc[k], 8);
    if (nvalid && l32 < 4) {
      float o[8];
      #pragma unroll
      for (int k = 0; k < 8; ++k) {
        float v = acc[k] * 0.25f + bias[8 * l32 + k];
        o[k] = v > 0.f ? v : expm1f(v);
      }
      float* op = hout + (size_t)node * 32 + 8 * l32;
      *(float4*)op       = make_float4(o[0], o[1], o[2], o[3]);
      *(float4*)(op + 4) = make_float4(o[4], o[5], o[6], o[7]);
    }
  } else {
    for (int nn = 0; nn < 2; ++nn) {
      int nd = nodeBase + nn;
      if (nd >= NNODES) break;
      int s2 = row_start[nd], e2 = row_start[nd + 1];
      float4 sd = *(const float4*)(scd + (size_t)nd * 4);
      float m0 = -INFINITY, m1 = -INFINITY, m2 = -INFINITY, m3 = -INFINITY;
      for (int i = s2 + lane; i < e2; i += 64) {
        int src = col_src[i];
        float4 ss = *(const float4*)(scs + (size_t)src * 4);
        m0 = fmaxf(m0, lrelu(ss.x + sd.x));
        m1 = fmaxf(m1, lrelu(ss.y + sd.y));
        m2 = fmaxf(m2, lrelu(ss.z + sd.z));
        m3 = fmaxf(m3, lrelu(ss.w + sd.w));
      }
      #pragma unroll
      for (int d = 32; d >= 1; d >>= 1) {
        m0 = fmaxf(m0, __shfl_xor(m0, d));
        m1 = fmaxf(m1, __shfl_xor(m1, d));
        m2 = fmaxf(m2, __shfl_xor(m2, d));
        m3 = fmaxf(m3, __shfl_xor(m3, d));
      }
      int g = lane >> 4, r = lane & 15, head = r >> 2;
      float den0 = 0, den1 = 0, den2 = 0, den3 = 0;
      float acc[8] = {};
      for (int base = s2; base < e2; base += 64) {
        int i = base + lane;
        bool valid = i < e2;
        int srcv = 0;
        float a0 = 0, a1 = 0, a2 = 0, a3 = 0;
        if (valid) {
          srcv = col_src[i];
          float4 ss = *(const float4*)(scs + (size_t)srcv * 4);
          a0 = __expf(lrelu(ss.x + sd.x) - m0);
          a1 = __expf(lrelu(ss.y + sd.y) - m1);
          a2 = __expf(lrelu(ss.z + sd.z) - m2);
          a3 = __expf(lrelu(ss.w + sd.w) - m3);
          den0 += a0; den1 += a1; den2 += a2; den3 += a3;
        }
        src_sh[wave][lane] = srcv;
        *(float4*)&al_sh[wave][lane * 4] = make_float4(a0, a1, a2, a3);
        int cnt = min(64, e2 - base);
        int ngc = (cnt + 3) >> 2;
        for (int jg = 0; jg < ngc; ++jg) {
          int j = jg * 4 + g;
          int src = src_sh[wave][j];
          float al = al_sh[wave][j * 4 + head];
          uint4 p = hp4[(size_t)src * 16 + r];
          float2 f0 = __half22float2(*(__half2*)&p.x);
          float2 f1 = __half22float2(*(__half2*)&p.y);
          float2 f2 = __half22float2(*(__half2*)&p.z);
          float2 f3 = __half22float2(*(__half2*)&p.w);
          acc[0] = fmaf(al, f0.x, acc[0]); acc[1] = fmaf(al, f0.y, acc[1]);
          acc[2] = fmaf(al, f1.x, acc[2]); acc[3] = fmaf(al, f1.y, acc[3]);
          acc[4] = fmaf(al, f2.x, acc[4]); acc[5] = fmaf(al, f2.y, acc[5]);
          acc[6] = fmaf(al, f3.x, acc[6]); acc[7] = fmaf(al, f3.y, acc[7]);
        }
      }
      #pragma unroll
      for (int d = 32; d >= 1; d >>= 1) {
        den0 += __shfl_xor(den0, d);
        den1 += __shfl_xor(den1, d);
        den2 += __shfl_xor(den2, d);
        den3 += __shfl_xor(den3, d);
      }
      float den = (head == 0) ? den0 : (head == 1) ? den1 : (head == 2) ? den2 : den3;
      float rd = 1.f / fmaxf(den, 1e-16f);
      #pragma unroll
      for (int k = 0; k < 8; ++k) acc[k] *= rd;
      #pragma unroll
      for (int d = 4; d <= 32; d <<= 1) {
        #pragma unroll
        for (int k = 0; k < 8; ++k) acc[k] += __shfl_xor(acc[k], d);
      }
      if (lane < 4) {
        float o[8];
        #pragma unroll
        for (int k = 0; k < 8; ++k) {
          float v = acc[k] * 0.25f + bias[8 * lane + k];
          o[k] = v > 0.f ? v : expm1f(v);
        }
        float* op = hout + (size_t)nd * 32 + 8 * lane;
        *(float4*)op       = make_float4(o[0], o[1], o[2], o[3]);
        *(float4*)(op + 4) = make_float4(o[4], o[5], o[6], o[7]);
      }
    }
  }
}

// ---------------- hierarchical global mean pool ----------------
#define POOL_BLOCKS 128
__global__ __launch_bounds__(256)
void pool_kernel(const float* __restrict__ h, const int* __restrict__ batch,
                 float* __restrict__ pooled, float* __restrict__ cnt) {
  __shared__ float acc[NGRAPH][HIDC];
  __shared__ float ccnt[NGRAPH];
  int tid = threadIdx.x;
  const int chunk = (NNODES + POOL_BLOCKS - 1) / POOL_BLOCKS;
  int n0 = blockIdx.x * chunk;
  int n1 = min(n0 + chunk, NNODES);
  if (n0 >= NNODES) return;
  int g0 = batch[n0], g1 = batch[n1 - 1];
  int rows = g1 - g0 + 1;
  for (int idx = tid; idx < rows * HIDC; idx += 256)
    acc[g0 + (idx >> 5)][idx & 31] = 0.f;
  for (int g = tid; g < rows; g += 256) ccnt[g0 + g] = 0.f;
  __syncthreads();
  int c = tid & 31;
  for (int node = n0 + (tid >> 5); node < n1; node += 8) {
    int g = batch[node];
    atomicAdd(&acc[g][c], h[(size_t)node * HIDC + c]);
    if (c == 0) atomicAdd(&ccnt[g], 1.f);
  }
  __syncthreads();
  for (int idx = tid; idx < rows * HIDC; idx += 256) {
    int g = g0 + (idx >> 5), cc = idx & 31;
    atomicAdd(&pooled[g * HIDC + cc], acc[g][cc]);
  }
  for (int g = tid; g < rows; g += 256) atomicAdd(&cnt[g0 + g], ccnt[g0 + g]);
}

__global__ void final_kernel(const float* __restrict__ pooled, const float* __restrict__ cnt,
                             const float* __restrict__ w, const float* __restrict__ b,
                             float* __restrict__ out) {
  int t = threadIdx.x;
  if (t >= NGRAPH * NCLS) return;
  int g = t / NCLS, j = t - g * NCLS;
  float inv = 1.f / fmaxf(cnt[g], 1.f);
  float acc = 0.f;
  #pragma unroll
  for (int c = 0; c < HIDC; ++c)
    acc = fmaf(pooled[g * HIDC + c], w[c * NCLS + j], acc);
  out[t] = acc * inv + b[j];
}

extern "C" void kernel_launch(void* const* d_in, const int* in_sizes, int n_in,
                              void* d_out, int out_size, void* d_ws, size_t ws_size,
                              hipStream_t stream) {
  const float* x      = (const float*)d_in[0];
  const int*   ei     = (const int*)d_in[1];
  const int*   batch  = (const int*)d_in[2];
  const float* enc1_w = (const float*)d_in[3];
  const float* enc1_b = (const float*)d_in[4];
  const float* enc2_w = (const float*)d_in[5];
  const float* enc2_b = (const float*)d_in[6];
  const float* lin1_w = (const float*)d_in[7];
  const float* lin1_b = (const float*)d_in[8];
  const float* gw[4]  = {(const float*)d_in[9],  (const float*)d_in[13], (const float*)d_in[17], (const float*)d_in[21]};
  const float* gas[4] = {(const float*)d_in[10], (const float*)d_in[14], (const float*)d_in[18], (const float*)d_in[22]};
  const float* gad[4] = {(const float*)d_in[11], (const float*)d_in[15], (const float*)d_in[19], (const float*)d_in[23]};
  const float* gb[4]  = {(const float*)d_in[12], (const float*)d_in[16], (const float*)d_in[20], (const float*)d_in[24]};
  float* out = (float*)d_out;

  __half* hproj_h   = (__half*)d_ws;                                // N*128 fp16
  _Float16* WT      = (_Float16*)(hproj_h + (size_t)NNODES * 128);  // 144*128 fp16
  float*  fws       = (float*)(WT + 144 * 128);
  float* hsmall = fws;                                        // N*32
  float* scs    = hsmall + (size_t)NNODES * 32;               // N*4
  float* scd    = scs    + (size_t)NNODES * 4;                // N*4
  float* pooled = scd    + (size_t)NNODES * 4;                // 64*32
  float* cnt    = pooled + NGRAPH * HIDC;                     // 64
  float* T1     = cnt + NGRAPH;                               // 128*256
  float* Wc     = T1 + 128 * 256;                             // 128*128
  float* b2c    = Wc + 128 * 128;                             // 256
  float* bc     = b2c + 256;                                  // 128
  float* soff1  = bc + 128;                                   // 8
  float* Ws2    = soff1 + 8;                                  // 32*8
  float* Ws3    = Ws2 + 32 * 8;
  float* Ws4    = Ws3 + 32 * 8;
  int* deg       = (int*)(Ws4 + 32 * 8);                      // N
  int* row_start = deg + NNODES;                              // N+1
  int* col_src   = row_start + NNODES + 1;                    // ETOT
  int* epos      = col_src + ETOT;                            // ETOT
  int* bsum      = epos + ETOT;                               // 196
  int* boff      = bsum + SCAN_BLOCKS;                        // 196

  // --- CSR build (atomic rank capture + atomic-free scatter) ---
  hipMemsetAsync(deg, 0, NNODES * sizeof(int), stream);
  hist_kernel<<<(ETOT + 1023) / 1024, 256, 0, stream>>>(ei, deg, epos);
  scan_block_kernel<<<SCAN_BLOCKS, 256, 0, stream>>>(deg, row_start, bsum);
  scan_sums_kernel<<<1, 256, 0, stream>>>(bsum, boff);
  scan_add_kernel<<<SCAN_BLOCKS, 256, 0, stream>>>(boff, row_start);
  scatter_kernel<<<(ETOT + 1023) / 1024, 256, 0, stream>>>(ei, row_start, epos, col_src);

  // --- weight composition (3 merged kernels; also zeroes pooled) ---
  wprep1<<<12, 256, 0, stream>>>(enc1_w, enc2_w, enc1_b, enc2_b,
                                 gw[1], gas[1], gad[1], gw[2], gas[2], gad[2],
                                 gw[3], gas[3], gad[3],
                                 T1, b2c, Ws2, Ws3, Ws4, pooled);
  wprep2<<<5, 256, 0, stream>>>(T1, gw[0], b2c, Wc, bc);
  wprep3<<<9, 256, 0, stream>>>(Wc, gas[0], gad[0], bc, WT, soff1);

  int nodeblocks64 = (NNODES + 63) / 64;
  int edgeblocks = (NNODES + 7) / 8;
  int psblocks   = (NNODES + PS_NODES - 1) / PS_NODES;

  // --- layer 1: MFMA composite projection + folded scores ---
  gemm_mfma<<<nodeblocks64, 256, 0, stream>>>(x, WT, bc, soff1, hproj_h, scs, scd);
  gat_edge_kernel<<<edgeblocks, 256, 0, stream>>>((const __half2*)hproj_h, scs, scd, row_start, col_src, gb[0], hsmall);

  // --- layers 2..4: fused register-resident projection + scores ---
  const float* WsL[3] = {Ws2, Ws3, Ws4};
  for (int L = 1; L < 4; ++L) {
    proj_scores_kernel<<<psblocks, 256, 0, stream>>>(hsmall, gw[L], WsL[L - 1], hproj_h, scs, scd);
    gat_edge_kernel<<<edgeblocks, 256, 0, stream>>>((const __half2*)hproj_h, scs, scd, row_start, col_src, gb[L], hsmall);
  }

  // --- pooling + classifier ---
  pool_kernel<<<POOL_BLOCKS, 256, 0, stream>>>(hsmall, batch, pooled, cnt);
  final_kernel<<<1, 640, 0, stream>>>(pooled, cnt, lin1_w, lin1_b, out);
}